// Round 1
// baseline (1107.547 us; speedup 1.0000x reference)
//
#include <hip/hip_runtime.h>
#include <math.h>

// GroupedQueryAttention: B=4,S=128,D=4096,H=32,KV=8,HD=128,REP=4
// Round 1: fp32 baseline. Vector-ALU bound (no fp32 MFMA on CDNA4).
// Plan: establish correctness + counters; round 2+ -> bf16x3 split MFMA GEMMs.

#define B_   4
#define S_   128
#define D_   4096
#define H_   32
#define KV_  8
#define HD_  128
#define M_   (B_ * S_)        // 512 rows
#define SCALE_ 0.088388347648318447f  // 1/sqrt(128)

// ---------------------------------------------------------------------------
// init: C[m,n] = bias[n]   (N is a power of two)
__global__ void init_bias_kernel(float* __restrict__ C,
                                 const float* __restrict__ bias,
                                 int nmask, int total) {
    int idx = blockIdx.x * 256 + threadIdx.x;
    if (idx < total) C[idx] = bias[idx & nmask];
}

// ---------------------------------------------------------------------------
// Generic fp32 GEMM with split-K atomic accumulate.
// C[M,N] += A[M,K] @ W[K,N].  Tile 128x128, BK=16, 256 threads, 8x8/thread
// using the 4+4 split mapping (rows ty*4..+3 and 64+ty*4..+3; cols same with
// tx) so LDS reads are 4-float-contiguous across 16 lanes (2-way alias, free).
__global__ __launch_bounds__(256, 2)
void gemm_splitk(const float* __restrict__ A, const float* __restrict__ W,
                 float* __restrict__ C, int M, int N, int K, int kslice) {
    __shared__ float As[16][132];   // [k][m] transposed, pad 132 (528B rows, 16B aligned)
    __shared__ float Ws[16][132];   // [k][n]

    const int tid = threadIdx.x;
    const int tx = tid & 15;        // n-dir
    const int ty = tid >> 4;        // m-dir
    const int m0 = blockIdx.y * 128;
    const int n0 = blockIdx.x * 128;
    const int k0 = blockIdx.z * kslice;

    float acc[8][8];
#pragma unroll
    for (int i = 0; i < 8; ++i)
#pragma unroll
        for (int j = 0; j < 8; ++j) acc[i][j] = 0.f;

    for (int kt = 0; kt < kslice; kt += 16) {
        const int k = k0 + kt;
        // stage A (transpose) and W (natural): 512 float4 tasks each, 2/thread
#pragma unroll
        for (int t = 0; t < 2; ++t) {
            int task = tid + t * 256;
            int ra = task >> 2, ca = task & 3;
            float4 a4 = *(const float4*)&A[(size_t)(m0 + ra) * K + k + ca * 4];
            As[ca * 4 + 0][ra] = a4.x; As[ca * 4 + 1][ra] = a4.y;
            As[ca * 4 + 2][ra] = a4.z; As[ca * 4 + 3][ra] = a4.w;
            int rw = task >> 5, cw = task & 31;
            float4 w4 = *(const float4*)&W[(size_t)(k + rw) * N + n0 + cw * 4];
            *(float4*)&Ws[rw][cw * 4] = w4;
        }
        __syncthreads();
#pragma unroll
        for (int kk = 0; kk < 16; ++kk) {
            float a[8], b[8];
            *(float4*)&a[0] = *(const float4*)&As[kk][ty * 4];
            *(float4*)&a[4] = *(const float4*)&As[kk][64 + ty * 4];
            *(float4*)&b[0] = *(const float4*)&Ws[kk][tx * 4];
            *(float4*)&b[4] = *(const float4*)&Ws[kk][64 + tx * 4];
#pragma unroll
            for (int i = 0; i < 8; ++i)
#pragma unroll
                for (int j = 0; j < 8; ++j)
                    acc[i][j] = fmaf(a[i], b[j], acc[i][j]);
        }
        __syncthreads();
    }
    // split-K accumulate (C pre-initialized with bias)
#pragma unroll
    for (int ih = 0; ih < 2; ++ih)
#pragma unroll
        for (int i = 0; i < 4; ++i) {
            int row = m0 + ih * 64 + ty * 4 + i;
#pragma unroll
            for (int jh = 0; jh < 2; ++jh) {
                float* cp = &C[(size_t)row * N + n0 + jh * 64 + tx * 4];
#pragma unroll
                for (int j = 0; j < 4; ++j)
                    atomicAdd(&cp[j], acc[ih * 4 + i][jh * 4 + j]);
            }
        }
}

// ---------------------------------------------------------------------------
// RoPE in place on t[(b*S+i)*nheads + h][HD], interleaved pairs.
__global__ void rope_kernel(float* __restrict__ t, const float* __restrict__ fc,
                            const float* __restrict__ fs, int nheads,
                            int total_pairs) {
    int p = blockIdx.x * 256 + threadIdx.x;
    if (p >= total_pairs) return;
    int d2 = p & 63;
    int rest = p >> 6;               // (b*S + i)*nheads + h
    int bi = rest / nheads;          // b*S + i
    int i = bi & (S_ - 1);
    float c = fc[i * 64 + d2], s = fs[i * 64 + d2];
    float re = t[2 * p], im = t[2 * p + 1];
    t[2 * p]     = re * c - im * s;
    t[2 * p + 1] = re * s + im * c;
}

// ---------------------------------------------------------------------------
// scores: P[bh][i][j] = scale * sum_d q[b,i,h,d]*k[b,j,kv,d] + mask[i][j]
// one block per (b,h); 128x128x128 mini-GEMM, same 8x8 per-thread structure.
__global__ __launch_bounds__(256, 2)
void attn_scores_kernel(const float* __restrict__ q, const float* __restrict__ kbuf,
                        const float* __restrict__ mask, float* __restrict__ P) {
    const int bh = blockIdx.x;
    const int b = bh >> 5, h = bh & 31, kv = h >> 2;
    __shared__ float Qs[16][132];
    __shared__ float Ks[16][132];
    const int tid = threadIdx.x;
    const int tx = tid & 15, ty = tid >> 4;

    float acc[8][8];
#pragma unroll
    for (int i = 0; i < 8; ++i)
#pragma unroll
        for (int j = 0; j < 8; ++j) acc[i][j] = 0.f;

    for (int d0 = 0; d0 < HD_; d0 += 16) {
#pragma unroll
        for (int t = 0; t < 2; ++t) {
            int task = tid + t * 256;
            int r = task >> 2, c = task & 3;
            int dd = d0 + c * 4;
            float4 a4 = *(const float4*)&q[((size_t)(b * S_ + r) * H_ + h) * HD_ + dd];
            Qs[c * 4 + 0][r] = a4.x; Qs[c * 4 + 1][r] = a4.y;
            Qs[c * 4 + 2][r] = a4.z; Qs[c * 4 + 3][r] = a4.w;
            float4 k4 = *(const float4*)&kbuf[((size_t)(b * S_ + r) * KV_ + kv) * HD_ + dd];
            Ks[c * 4 + 0][r] = k4.x; Ks[c * 4 + 1][r] = k4.y;
            Ks[c * 4 + 2][r] = k4.z; Ks[c * 4 + 3][r] = k4.w;
        }
        __syncthreads();
#pragma unroll
        for (int kk = 0; kk < 16; ++kk) {
            float a[8], bb[8];
            *(float4*)&a[0]  = *(const float4*)&Qs[kk][ty * 4];
            *(float4*)&a[4]  = *(const float4*)&Qs[kk][64 + ty * 4];
            *(float4*)&bb[0] = *(const float4*)&Ks[kk][tx * 4];
            *(float4*)&bb[4] = *(const float4*)&Ks[kk][64 + tx * 4];
#pragma unroll
            for (int i = 0; i < 8; ++i)
#pragma unroll
                for (int j = 0; j < 8; ++j)
                    acc[i][j] = fmaf(a[i], bb[j], acc[i][j]);
        }
        __syncthreads();
    }
#pragma unroll
    for (int ih = 0; ih < 2; ++ih)
#pragma unroll
        for (int i = 0; i < 4; ++i) {
            int row = ih * 64 + ty * 4 + i;
#pragma unroll
            for (int jh = 0; jh < 2; ++jh) {
                int col = jh * 64 + tx * 4;
                float4 r4;
                r4.x = acc[ih*4+i][jh*4+0] * SCALE_ + mask[row * S_ + col + 0];
                r4.y = acc[ih*4+i][jh*4+1] * SCALE_ + mask[row * S_ + col + 1];
                r4.z = acc[ih*4+i][jh*4+2] * SCALE_ + mask[row * S_ + col + 2];
                r4.w = acc[ih*4+i][jh*4+3] * SCALE_ + mask[row * S_ + col + 3];
                *(float4*)&P[((size_t)bh * S_ + row) * S_ + col] = r4;
            }
        }
}

// ---------------------------------------------------------------------------
// softmax over rows of length 128; one wave (64 lanes) per row.
__global__ void softmax_kernel(float* __restrict__ P, int rows) {
    int r = blockIdx.x * 4 + (threadIdx.x >> 6);
    if (r >= rows) return;
    int lane = threadIdx.x & 63;
    float* row = P + (size_t)r * 128;
    float x0 = row[lane], x1 = row[lane + 64];
    float m = fmaxf(x0, x1);
#pragma unroll
    for (int off = 32; off >= 1; off >>= 1)
        m = fmaxf(m, __shfl_xor(m, off, 64));
    float e0 = expf(x0 - m), e1 = expf(x1 - m);
    float s = e0 + e1;
#pragma unroll
    for (int off = 32; off >= 1; off >>= 1)
        s += __shfl_xor(s, off, 64);
    float inv = 1.0f / s;
    row[lane] = e0 * inv;
    row[lane + 64] = e1 * inv;
}

// ---------------------------------------------------------------------------
// PV: attn[b,i,h,:] = P[bh] @ V[b,:,kv,:]; one block per (b,h).
__global__ __launch_bounds__(256, 2)
void attn_pv_kernel(const float* __restrict__ P, const float* __restrict__ vbuf,
                    float* __restrict__ attn) {
    const int bh = blockIdx.x;
    const int b = bh >> 5, h = bh & 31, kv = h >> 2;
    __shared__ float Ps[16][132];   // [j][i] transposed
    __shared__ float Vs[16][132];   // [j][d]
    const int tid = threadIdx.x;
    const int tx = tid & 15, ty = tid >> 4;

    float acc[8][8];
#pragma unroll
    for (int i = 0; i < 8; ++i)
#pragma unroll
        for (int j = 0; j < 8; ++j) acc[i][j] = 0.f;

    for (int j0 = 0; j0 < S_; j0 += 16) {
#pragma unroll
        for (int t = 0; t < 2; ++t) {
            int task = tid + t * 256;
            int r = task >> 2, c = task & 3;
            float4 p4 = *(const float4*)&P[((size_t)bh * S_ + r) * S_ + j0 + c * 4];
            Ps[c * 4 + 0][r] = p4.x; Ps[c * 4 + 1][r] = p4.y;
            Ps[c * 4 + 2][r] = p4.z; Ps[c * 4 + 3][r] = p4.w;
            int rw = task >> 5, cw = task & 31;
            float4 v4 = *(const float4*)&vbuf[((size_t)(b * S_ + j0 + rw) * KV_ + kv) * HD_ + cw * 4];
            *(float4*)&Vs[rw][cw * 4] = v4;
        }
        __syncthreads();
#pragma unroll
        for (int kk = 0; kk < 16; ++kk) {
            float a[8], bb[8];
            *(float4*)&a[0]  = *(const float4*)&Ps[kk][ty * 4];
            *(float4*)&a[4]  = *(const float4*)&Ps[kk][64 + ty * 4];
            *(float4*)&bb[0] = *(const float4*)&Vs[kk][tx * 4];
            *(float4*)&bb[4] = *(const float4*)&Vs[kk][64 + tx * 4];
#pragma unroll
            for (int i = 0; i < 8; ++i)
#pragma unroll
                for (int j = 0; j < 8; ++j)
                    acc[i][j] = fmaf(a[i], bb[j], acc[i][j]);
        }
        __syncthreads();
    }
#pragma unroll
    for (int ih = 0; ih < 2; ++ih)
#pragma unroll
        for (int i = 0; i < 4; ++i) {
            int row = ih * 64 + ty * 4 + i;
#pragma unroll
            for (int jh = 0; jh < 2; ++jh) {
                int col = jh * 64 + tx * 4;
                float4 r4;
                r4.x = acc[ih*4+i][jh*4+0];
                r4.y = acc[ih*4+i][jh*4+1];
                r4.z = acc[ih*4+i][jh*4+2];
                r4.w = acc[ih*4+i][jh*4+3];
                *(float4*)&attn[((size_t)(b * S_ + row)) * (H_ * HD_) + h * HD_ + col] = r4;
            }
        }
}

// ---------------------------------------------------------------------------
extern "C" void kernel_launch(void* const* d_in, const int* in_sizes, int n_in,
                              void* d_out, int out_size, void* d_ws, size_t ws_size,
                              hipStream_t stream) {
    const float* x    = (const float*)d_in[0];
    // d_in[1] start_pos == 0 (unused); d_in[5]/d_in[6] caches unused (not returned)
    const float* fc   = (const float*)d_in[2];
    const float* fs   = (const float*)d_in[3];
    const float* mask = (const float*)d_in[4];
    const float* wq   = (const float*)d_in[7];
    const float* bq   = (const float*)d_in[8];
    const float* wk   = (const float*)d_in[9];
    const float* bk   = (const float*)d_in[10];
    const float* wv   = (const float*)d_in[11];
    const float* bv   = (const float*)d_in[12];
    const float* wo   = (const float*)d_in[13];
    const float* bo   = (const float*)d_in[14];
    float* out = (float*)d_out;

    float* ws   = (float*)d_ws;
    float* qb   = ws;                    // 512*4096 = 2097152
    float* kb   = qb + 2097152;          // 512*1024 =  524288
    float* vb   = kb + 524288;           //            524288
    float* Pb   = vb + 524288;           // 4*32*128*128 = 2097152
    float* atb  = Pb + 2097152;          // 2097152  (total 28 MB)

    // --- Q/K/V projections (bias-init + split-K atomic GEMM) ---
    init_bias_kernel<<<8192, 256, 0, stream>>>(qb, bq, 4095, 2097152);
    gemm_splitk<<<dim3(32, 4, 4), 256, 0, stream>>>(x, wq, qb, M_, 4096, D_, 1024);
    init_bias_kernel<<<2048, 256, 0, stream>>>(kb, bk, 1023, 524288);
    gemm_splitk<<<dim3(8, 4, 16), 256, 0, stream>>>(x, wk, kb, M_, 1024, D_, 256);
    init_bias_kernel<<<2048, 256, 0, stream>>>(vb, bv, 1023, 524288);
    gemm_splitk<<<dim3(8, 4, 16), 256, 0, stream>>>(x, wv, vb, M_, 1024, D_, 256);

    // --- RoPE on q and k ---
    rope_kernel<<<4096, 256, 0, stream>>>(qb, fc, fs, H_, 1048576);
    rope_kernel<<<1024, 256, 0, stream>>>(kb, fc, fs, KV_, 262144);

    // --- attention ---
    attn_scores_kernel<<<B_ * H_, 256, 0, stream>>>(qb, kb, mask, Pb);
    softmax_kernel<<<4096, 256, 0, stream>>>(Pb, B_ * H_ * S_);
    attn_pv_kernel<<<B_ * H_, 256, 0, stream>>>(Pb, vb, atb);

    // --- output projection ---
    init_bias_kernel<<<8192, 256, 0, stream>>>(out, bo, 4095, 2097152);
    gemm_splitk<<<dim3(32, 4, 4), 256, 0, stream>>>(atb, wo, out, M_, 4096, D_, 1024);
}

// Round 2
// 507.867 us; speedup vs baseline: 2.1808x; 2.1808x over previous
//
#include <hip/hip_runtime.h>
#include <math.h>

// GroupedQueryAttention: B=4,S=128,D=4096,H=32,KV=8,HD=128,REP=4
// Round 2: projections via bf16 hi/lo split MFMA (3-term, ~fp32 accuracy).
// Attention trio still fp32 vector (next round's target).

#define B_   4
#define S_   128
#define D_   4096
#define H_   32
#define KV_  8
#define HD_  128
#define M_   (B_ * S_)        // 512 rows
#define SCALE_ 0.088388347648318447f  // 1/sqrt(128)

typedef __bf16 bf16x8 __attribute__((ext_vector_type(8)));
typedef float  f32x4  __attribute__((ext_vector_type(4)));
typedef unsigned short ushort;

__device__ inline void split2(float f, ushort& h, ushort& l) {
    __bf16 hb = (__bf16)f;
    float hf = (float)hb;
    __bf16 lb = (__bf16)(f - hf);
    h = __builtin_bit_cast(ushort, hb);
    l = __builtin_bit_cast(ushort, lb);
}

// ---------------------------------------------------------------------------
// C[m,n] = bias[n]   (N is a power of two)
__global__ void init_bias_kernel(float* __restrict__ C,
                                 const float* __restrict__ bias,
                                 int nmask, int total) {
    int idx = blockIdx.x * 256 + threadIdx.x;
    if (idx < total) C[idx] = bias[idx & nmask];
}

// ---------------------------------------------------------------------------
// fp32 [R][C] -> bf16 hi/lo same layout (grid-stride over float4 groups)
__global__ void convert_split_kernel(const float* __restrict__ in,
                                     ushort* __restrict__ h, ushort* __restrict__ l,
                                     int total4) {
    int i = blockIdx.x * 256 + threadIdx.x;
    if (i >= total4) return;
    float4 f = ((const float4*)in)[i];
    __align__(8) ushort hs[4], ls[4];
    split2(f.x, hs[0], ls[0]); split2(f.y, hs[1], ls[1]);
    split2(f.z, hs[2], ls[2]); split2(f.w, hs[3], ls[3]);
    ((uint2*)h)[i] = *(uint2*)hs;
    ((uint2*)l)[i] = *(uint2*)ls;
}

// ---------------------------------------------------------------------------
// W [K][N] fp32 -> Th, Tl [N][K] bf16 (transpose + split). 64x64 tiles.
__global__ __launch_bounds__(256)
void transpose_split_kernel(const float* __restrict__ W, ushort* __restrict__ Th,
                            ushort* __restrict__ Tl, int N, int K) {
    __shared__ float tile[64][65];
    const int t = threadIdx.x;
    const int k0 = blockIdx.y * 64, n0 = blockIdx.x * 64;
#pragma unroll
    for (int p = 0; p < 4; ++p) {
        int idx = t + p * 256;        // 0..1023 float4 tasks
        int r = idx >> 4;             // k-row 0..63
        int c4 = idx & 15;            // float4 col
        float4 w4 = *(const float4*)&W[(size_t)(k0 + r) * N + n0 + c4 * 4];
        tile[r][c4 * 4 + 0] = w4.x; tile[r][c4 * 4 + 1] = w4.y;
        tile[r][c4 * 4 + 2] = w4.z; tile[r][c4 * 4 + 3] = w4.w;
    }
    __syncthreads();
    const int n = t >> 2, kq = t & 3;       // n-row, k-quarter (16 k each)
    __align__(16) ushort hs[16], ls[16];
#pragma unroll
    for (int i = 0; i < 16; ++i)
        split2(tile[kq * 16 + i][n], hs[i], ls[i]);
    size_t ob = (size_t)(n0 + n) * K + k0 + kq * 16;
    *(uint4*)&Th[ob]     = *(uint4*)&hs[0];
    *(uint4*)&Th[ob + 8] = *(uint4*)&hs[8];
    *(uint4*)&Tl[ob]     = *(uint4*)&ls[0];
    *(uint4*)&Tl[ob + 8] = *(uint4*)&ls[8];
}

// ---------------------------------------------------------------------------
// C[M,N] += A[M,K] @ W[K,N] with A given as hi/lo bf16 [M][K] and W as
// hi/lo bf16 TRANSPOSED [N][K]. 3-term split MFMA 16x16x32.
// Tile 128x128, BK=32, 4 waves (2x2 of 64x64), split-K via fp32 atomics.
__global__ __launch_bounds__(256, 2)
void gemm_bf3(const ushort* __restrict__ Ah, const ushort* __restrict__ Al,
              const ushort* __restrict__ Bh, const ushort* __restrict__ Bl,
              float* __restrict__ C, int N, int K, int kslice) {
    __shared__ ushort AsH[128][40], AsL[128][40], BsH[128][40], BsL[128][40];
    const int tid = threadIdx.x;
    const int m0 = blockIdx.y * 128, n0 = blockIdx.x * 128;
    const int kbase = blockIdx.z * kslice;
    const int w = tid >> 6, lane = tid & 63;
    const int quad = lane >> 4, l16 = lane & 15;
    const int wm = (w & 1) * 64, wn = (w >> 1) * 64;
    const int r = tid >> 2, q = tid & 3;    // staging: row 0..63(+64), k-octet

    f32x4 acc[4][4] = {};

    for (int kc = kbase; kc < kbase + kslice; kc += 32) {
#pragma unroll
        for (int p = 0; p < 2; ++p) {
            int row = r + p * 64;
            size_t ga = (size_t)(m0 + row) * K + kc + q * 8;
            *(uint4*)&AsH[row][q * 8] = *(const uint4*)&Ah[ga];
            *(uint4*)&AsL[row][q * 8] = *(const uint4*)&Al[ga];
            size_t gb = (size_t)(n0 + row) * K + kc + q * 8;
            *(uint4*)&BsH[row][q * 8] = *(const uint4*)&Bh[gb];
            *(uint4*)&BsL[row][q * 8] = *(const uint4*)&Bl[gb];
        }
        __syncthreads();
        bf16x8 ah[4], al[4], bh[4], bl[4];
#pragma unroll
        for (int i = 0; i < 4; ++i) {
            ah[i] = *(const bf16x8*)&AsH[wm + i * 16 + l16][quad * 8];
            al[i] = *(const bf16x8*)&AsL[wm + i * 16 + l16][quad * 8];
            bh[i] = *(const bf16x8*)&BsH[wn + i * 16 + l16][quad * 8];
            bl[i] = *(const bf16x8*)&BsL[wn + i * 16 + l16][quad * 8];
        }
#pragma unroll
        for (int i = 0; i < 4; ++i)
#pragma unroll
            for (int j = 0; j < 4; ++j) {
                acc[i][j] = __builtin_amdgcn_mfma_f32_16x16x32_bf16(ah[i], bh[j], acc[i][j], 0, 0, 0);
                acc[i][j] = __builtin_amdgcn_mfma_f32_16x16x32_bf16(ah[i], bl[j], acc[i][j], 0, 0, 0);
                acc[i][j] = __builtin_amdgcn_mfma_f32_16x16x32_bf16(al[i], bh[j], acc[i][j], 0, 0, 0);
            }
        __syncthreads();
    }
    // epilogue: C/D layout col=lane&15, row=quad*4+reg
#pragma unroll
    for (int i = 0; i < 4; ++i)
#pragma unroll
        for (int j = 0; j < 4; ++j) {
            int col = n0 + wn + j * 16 + l16;
#pragma unroll
            for (int rg = 0; rg < 4; ++rg) {
                int rowm = m0 + wm + i * 16 + quad * 4 + rg;
                atomicAdd(&C[(size_t)rowm * N + col], acc[i][j][rg]);
            }
        }
}

// ---------------------------------------------------------------------------
// RoPE in place on t[(b*S+i)*nheads + h][HD], interleaved pairs.
__global__ void rope_kernel(float* __restrict__ t, const float* __restrict__ fc,
                            const float* __restrict__ fs, int nheads,
                            int total_pairs) {
    int p = blockIdx.x * 256 + threadIdx.x;
    if (p >= total_pairs) return;
    int d2 = p & 63;
    int rest = p >> 6;               // (b*S + i)*nheads + h
    int bi = rest / nheads;          // b*S + i
    int i = bi & (S_ - 1);
    float c = fc[i * 64 + d2], s = fs[i * 64 + d2];
    float re = t[2 * p], im = t[2 * p + 1];
    t[2 * p]     = re * c - im * s;
    t[2 * p + 1] = re * s + im * c;
}

// ---------------------------------------------------------------------------
// scores: P[bh][i][j] = scale * sum_d q[b,i,h,d]*k[b,j,kv,d] + mask[i][j]
__global__ __launch_bounds__(256, 2)
void attn_scores_kernel(const float* __restrict__ q, const float* __restrict__ kbuf,
                        const float* __restrict__ mask, float* __restrict__ P) {
    const int bh = blockIdx.x;
    const int b = bh >> 5, h = bh & 31, kv = h >> 2;
    __shared__ float Qs[16][132];
    __shared__ float Ks[16][132];
    const int tid = threadIdx.x;
    const int tx = tid & 15, ty = tid >> 4;

    float acc[8][8];
#pragma unroll
    for (int i = 0; i < 8; ++i)
#pragma unroll
        for (int j = 0; j < 8; ++j) acc[i][j] = 0.f;

    for (int d0 = 0; d0 < HD_; d0 += 16) {
#pragma unroll
        for (int t = 0; t < 2; ++t) {
            int task = tid + t * 256;
            int rr = task >> 2, c = task & 3;
            int dd = d0 + c * 4;
            float4 a4 = *(const float4*)&q[((size_t)(b * S_ + rr) * H_ + h) * HD_ + dd];
            Qs[c * 4 + 0][rr] = a4.x; Qs[c * 4 + 1][rr] = a4.y;
            Qs[c * 4 + 2][rr] = a4.z; Qs[c * 4 + 3][rr] = a4.w;
            float4 k4 = *(const float4*)&kbuf[((size_t)(b * S_ + rr) * KV_ + kv) * HD_ + dd];
            Ks[c * 4 + 0][rr] = k4.x; Ks[c * 4 + 1][rr] = k4.y;
            Ks[c * 4 + 2][rr] = k4.z; Ks[c * 4 + 3][rr] = k4.w;
        }
        __syncthreads();
#pragma unroll
        for (int kk = 0; kk < 16; ++kk) {
            float a[8], bb[8];
            *(float4*)&a[0]  = *(const float4*)&Qs[kk][ty * 4];
            *(float4*)&a[4]  = *(const float4*)&Qs[kk][64 + ty * 4];
            *(float4*)&bb[0] = *(const float4*)&Ks[kk][tx * 4];
            *(float4*)&bb[4] = *(const float4*)&Ks[kk][64 + tx * 4];
#pragma unroll
            for (int i = 0; i < 8; ++i)
#pragma unroll
                for (int j = 0; j < 8; ++j)
                    acc[i][j] = fmaf(a[i], bb[j], acc[i][j]);
        }
        __syncthreads();
    }
#pragma unroll
    for (int ih = 0; ih < 2; ++ih)
#pragma unroll
        for (int i = 0; i < 4; ++i) {
            int row = ih * 64 + ty * 4 + i;
#pragma unroll
            for (int jh = 0; jh < 2; ++jh) {
                int col = jh * 64 + tx * 4;
                float4 r4;
                r4.x = acc[ih*4+i][jh*4+0] * SCALE_ + mask[row * S_ + col + 0];
                r4.y = acc[ih*4+i][jh*4+1] * SCALE_ + mask[row * S_ + col + 1];
                r4.z = acc[ih*4+i][jh*4+2] * SCALE_ + mask[row * S_ + col + 2];
                r4.w = acc[ih*4+i][jh*4+3] * SCALE_ + mask[row * S_ + col + 3];
                *(float4*)&P[((size_t)bh * S_ + row) * S_ + col] = r4;
            }
        }
}

// ---------------------------------------------------------------------------
// softmax over rows of length 128; one wave per row.
__global__ void softmax_kernel(float* __restrict__ P, int rows) {
    int rI = blockIdx.x * 4 + (threadIdx.x >> 6);
    if (rI >= rows) return;
    int lane = threadIdx.x & 63;
    float* row = P + (size_t)rI * 128;
    float x0 = row[lane], x1 = row[lane + 64];
    float m = fmaxf(x0, x1);
#pragma unroll
    for (int off = 32; off >= 1; off >>= 1)
        m = fmaxf(m, __shfl_xor(m, off, 64));
    float e0 = expf(x0 - m), e1 = expf(x1 - m);
    float s = e0 + e1;
#pragma unroll
    for (int off = 32; off >= 1; off >>= 1)
        s += __shfl_xor(s, off, 64);
    float inv = 1.0f / s;
    row[lane] = e0 * inv;
    row[lane + 64] = e1 * inv;
}

// ---------------------------------------------------------------------------
// PV: attn[b,i,h,:] = P[bh] @ V[b,:,kv,:]
__global__ __launch_bounds__(256, 2)
void attn_pv_kernel(const float* __restrict__ P, const float* __restrict__ vbuf,
                    float* __restrict__ attn) {
    const int bh = blockIdx.x;
    const int b = bh >> 5, h = bh & 31, kv = h >> 2;
    __shared__ float Ps[16][132];
    __shared__ float Vs[16][132];
    const int tid = threadIdx.x;
    const int tx = tid & 15, ty = tid >> 4;

    float acc[8][8];
#pragma unroll
    for (int i = 0; i < 8; ++i)
#pragma unroll
        for (int j = 0; j < 8; ++j) acc[i][j] = 0.f;

    for (int j0 = 0; j0 < S_; j0 += 16) {
#pragma unroll
        for (int t = 0; t < 2; ++t) {
            int task = tid + t * 256;
            int rr = task >> 2, c = task & 3;
            float4 p4 = *(const float4*)&P[((size_t)bh * S_ + rr) * S_ + j0 + c * 4];
            Ps[c * 4 + 0][rr] = p4.x; Ps[c * 4 + 1][rr] = p4.y;
            Ps[c * 4 + 2][rr] = p4.z; Ps[c * 4 + 3][rr] = p4.w;
            int rw = task >> 5, cw = task & 31;
            float4 v4 = *(const float4*)&vbuf[((size_t)(b * S_ + j0 + rw) * KV_ + kv) * HD_ + cw * 4];
            *(float4*)&Vs[rw][cw * 4] = v4;
        }
        __syncthreads();
#pragma unroll
        for (int kk = 0; kk < 16; ++kk) {
            float a[8], bb[8];
            *(float4*)&a[0]  = *(const float4*)&Ps[kk][ty * 4];
            *(float4*)&a[4]  = *(const float4*)&Ps[kk][64 + ty * 4];
            *(float4*)&bb[0] = *(const float4*)&Vs[kk][tx * 4];
            *(float4*)&bb[4] = *(const float4*)&Vs[kk][64 + tx * 4];
#pragma unroll
            for (int i = 0; i < 8; ++i)
#pragma unroll
                for (int j = 0; j < 8; ++j)
                    acc[i][j] = fmaf(a[i], bb[j], acc[i][j]);
        }
        __syncthreads();
    }
#pragma unroll
    for (int ih = 0; ih < 2; ++ih)
#pragma unroll
        for (int i = 0; i < 4; ++i) {
            int row = ih * 64 + ty * 4 + i;
#pragma unroll
            for (int jh = 0; jh < 2; ++jh) {
                int col = jh * 64 + tx * 4;
                float4 r4;
                r4.x = acc[ih*4+i][jh*4+0];
                r4.y = acc[ih*4+i][jh*4+1];
                r4.z = acc[ih*4+i][jh*4+2];
                r4.w = acc[ih*4+i][jh*4+3];
                *(float4*)&attn[((size_t)(b * S_ + row)) * (H_ * HD_) + h * HD_ + col] = r4;
            }
        }
}

// ---------------------------------------------------------------------------
extern "C" void kernel_launch(void* const* d_in, const int* in_sizes, int n_in,
                              void* d_out, int out_size, void* d_ws, size_t ws_size,
                              hipStream_t stream) {
    const float* x    = (const float*)d_in[0];
    const float* fc   = (const float*)d_in[2];
    const float* fs   = (const float*)d_in[3];
    const float* mask = (const float*)d_in[4];
    const float* wq   = (const float*)d_in[7];
    const float* bq   = (const float*)d_in[8];
    const float* wk   = (const float*)d_in[9];
    const float* bk   = (const float*)d_in[10];
    const float* wv   = (const float*)d_in[11];
    const float* bv   = (const float*)d_in[12];
    const float* wo   = (const float*)d_in[13];
    const float* bo   = (const float*)d_in[14];
    float* out = (float*)d_out;

    float* ws = (float*)d_ws;
    float*  qb  = ws;                       // 2,097,152 f
    float*  kb  = qb + 2097152;             //   524,288 f
    float*  vb  = kb + 524288;              //   524,288 f
    float*  Pb  = vb + 524288;              // 2,097,152 f
    float*  atb = Pb + 2097152;             // 2,097,152 f
    ushort* xh  = (ushort*)(atb + 2097152); // 2M bf16 (1,048,576 f)
    ushort* xl  = xh + 2097152;             // 2M bf16
    ushort* WtH = xl + 2097152;             // up to 16M bf16
    ushort* WtL = WtH + 16777216;           // up to 16M bf16  (total ~100 MB)

    // --- split x into bf16 hi/lo ---
    convert_split_kernel<<<2048, 256, 0, stream>>>(x, xh, xl, 524288);

    // --- Q projection: N=4096 ---
    transpose_split_kernel<<<dim3(64, 64), 256, 0, stream>>>(wq, WtH, WtL, 4096, 4096);
    init_bias_kernel<<<8192, 256, 0, stream>>>(qb, bq, 4095, 2097152);
    gemm_bf3<<<dim3(32, 4, 4), 256, 0, stream>>>(xh, xl, WtH, WtL, qb, 4096, 4096, 1024);

    // --- K projection: N=1024 ---
    transpose_split_kernel<<<dim3(16, 64), 256, 0, stream>>>(wk, WtH, WtL, 1024, 4096);
    init_bias_kernel<<<2048, 256, 0, stream>>>(kb, bk, 1023, 524288);
    gemm_bf3<<<dim3(8, 4, 8), 256, 0, stream>>>(xh, xl, WtH, WtL, kb, 1024, 4096, 512);

    // --- V projection: N=1024 ---
    transpose_split_kernel<<<dim3(16, 64), 256, 0, stream>>>(wv, WtH, WtL, 1024, 4096);
    init_bias_kernel<<<2048, 256, 0, stream>>>(vb, bv, 1023, 524288);
    gemm_bf3<<<dim3(8, 4, 8), 256, 0, stream>>>(xh, xl, WtH, WtL, vb, 1024, 4096, 512);

    // --- RoPE ---
    rope_kernel<<<4096, 256, 0, stream>>>(qb, fc, fs, H_, 1048576);
    rope_kernel<<<1024, 256, 0, stream>>>(kb, fc, fs, KV_, 262144);

    // --- attention (fp32, unchanged) ---
    attn_scores_kernel<<<B_ * H_, 256, 0, stream>>>(qb, kb, mask, Pb);
    softmax_kernel<<<4096, 256, 0, stream>>>(Pb, B_ * H_ * S_);
    attn_pv_kernel<<<B_ * H_, 256, 0, stream>>>(Pb, vb, atb);

    // --- output projection: reuse xh/xl for split(atb) ---
    convert_split_kernel<<<2048, 256, 0, stream>>>(atb, xh, xl, 524288);
    transpose_split_kernel<<<dim3(64, 64), 256, 0, stream>>>(wo, WtH, WtL, 4096, 4096);
    init_bias_kernel<<<8192, 256, 0, stream>>>(out, bo, 4095, 2097152);
    gemm_bf3<<<dim3(32, 4, 4), 256, 0, stream>>>(xh, xl, WtH, WtL, out, 4096, 4096, 1024);
}

// Round 3
// 425.085 us; speedup vs baseline: 2.6055x; 1.1947x over previous
//
#include <hip/hip_runtime.h>
#include <math.h>

// GroupedQueryAttention: B=4,S=128,D=4096,H=32,KV=8,HD=128,REP=4
// Round 3: fp16 1-term MFMA projections, fused QKV (N=6144), XOR-swizzled
// LDS + global_load_lds(16B) staging. Attention trio still fp32 vector.

#define B_   4
#define S_   128
#define D_   4096
#define H_   32
#define KV_  8
#define HD_  128
#define M_   (B_ * S_)        // 512 rows
#define NQKV 6144
#define SCALE_ 0.088388347648318447f  // 1/sqrt(128)

typedef _Float16 half_t;
typedef half_t f16x8 __attribute__((ext_vector_type(8)));
typedef float  f32x4 __attribute__((ext_vector_type(4)));
typedef unsigned short ushort;

__device__ inline void load_lds16(const void* g, void* l) {
    __builtin_amdgcn_global_load_lds((const __attribute__((address_space(1))) void*)g,
                                     (__attribute__((address_space(3))) void*)l,
                                     16, 0, 0);
}

// ---------------------------------------------------------------------------
// out[m,n] = bias[n], pow2 N (for out-proj C)
__global__ void init_bias_kernel(float* __restrict__ C,
                                 const float* __restrict__ bias,
                                 int nmask, int total) {
    int idx = blockIdx.x * 256 + threadIdx.x;
    if (idx < total) C[idx] = bias[idx & nmask];
}

// qkv C [512][6144] = concat bias  (grid: x=24 col-chunks, y=512 rows)
__global__ void init_qkv_bias(float* __restrict__ C, const float* __restrict__ bq,
                              const float* __restrict__ bk, const float* __restrict__ bv) {
    int col = blockIdx.x * 256 + threadIdx.x;
    int row = blockIdx.y;
    float v = (col < 4096) ? bq[col] : (col < 5120) ? bk[col - 4096] : bv[col - 5120];
    C[(size_t)row * NQKV + col] = v;
}

// ---------------------------------------------------------------------------
// fp32 -> fp16 (float4 granules)
__global__ void convert_f16(const float* __restrict__ in, half_t* __restrict__ out,
                            int total4) {
    int i = blockIdx.x * 256 + threadIdx.x;
    if (i >= total4) return;
    float4 f = ((const float4*)in)[i];
    __align__(8) half_t h4[4] = {(half_t)f.x, (half_t)f.y, (half_t)f.z, (half_t)f.w};
    ((uint2*)out)[i] = *(uint2*)h4;
}

// ---------------------------------------------------------------------------
// Fused W [K][Nsrc] fp32 -> Wt [6144][4096] fp16 transposed. 64x64 tiles.
// grid.x: 0-63 -> wq (N=4096), 64-79 -> wk, 80-95 -> wv.  For wo: grid.x=64
// with wq=wo.
__global__ __launch_bounds__(256)
void transpose_qkv(const float* __restrict__ wq, const float* __restrict__ wk,
                   const float* __restrict__ wv, half_t* __restrict__ Wt) {
    __shared__ float tile[64][65];
    const int t = threadIdx.x;
    const int nt = blockIdx.x, k0 = blockIdx.y * 64;
    const float* src; int Nsrc, nsrc0, ndst0;
    if (nt < 64)      { src = wq; Nsrc = 4096; nsrc0 = nt * 64;        ndst0 = nt * 64; }
    else if (nt < 80) { src = wk; Nsrc = 1024; nsrc0 = (nt - 64) * 64; ndst0 = 4096 + (nt - 64) * 64; }
    else              { src = wv; Nsrc = 1024; nsrc0 = (nt - 80) * 64; ndst0 = 5120 + (nt - 80) * 64; }
#pragma unroll
    for (int p = 0; p < 4; ++p) {
        int idx = t + p * 256;
        int r = idx >> 4, c4 = idx & 15;
        float4 w4 = *(const float4*)&src[(size_t)(k0 + r) * Nsrc + nsrc0 + c4 * 4];
        tile[r][c4 * 4 + 0] = w4.x; tile[r][c4 * 4 + 1] = w4.y;
        tile[r][c4 * 4 + 2] = w4.z; tile[r][c4 * 4 + 3] = w4.w;
    }
    __syncthreads();
    const int n = t >> 2, kq = t & 3;
    __align__(16) half_t hs[16];
#pragma unroll
    for (int i = 0; i < 16; ++i)
        hs[i] = (half_t)tile[kq * 16 + i][n];
    size_t ob = (size_t)(ndst0 + n) * 4096 + k0 + kq * 16;
    *(uint4*)&Wt[ob]     = *(uint4*)&hs[0];
    *(uint4*)&Wt[ob + 8] = *(uint4*)&hs[8];
}

// ---------------------------------------------------------------------------
// C[M,N] += A16[M,K] @ Bt[N,K]^T, fp16 inputs, fp32 atomic accumulate.
// Tile 128x128, BK=64, 4 waves (2x2 of 64x64), split-K z.
// LDS: physically linear [128][64] halfs; logical 16B-octet L of row r lives
// at physical octet L^(r&7) (source-side permutation keeps the DMA writes
// linear/conflict-free; fragment reads land 2-way = free).
__global__ __launch_bounds__(256, 3)
void gemm_f16(const half_t* __restrict__ A16, const half_t* __restrict__ Bt,
              float* __restrict__ C, int N, int K, int kslice) {
    __shared__ __align__(16) half_t As[128][64];
    __shared__ __align__(16) half_t Bs[128][64];
    const int tid = threadIdx.x;
    const int m0 = blockIdx.y * 128, n0 = blockIdx.x * 128;
    const int kbase = blockIdx.z * kslice;
    const int lane = tid & 63;
    const int quad = lane >> 4, l16 = lane & 15;
    const int w = tid >> 6;
    const int wm = (w & 1) * 64, wn = (w >> 1) * 64;
    const int tB = tid & 192;     // wave-uniform task base

    f32x4 acc[4][4] = {};

    for (int kc = kbase; kc < kbase + kslice; kc += 64) {
#pragma unroll
        for (int p = 0; p < 4; ++p) {
            int tb = p * 256 + tB;        // uniform within wave
            int task = tb + lane;
            int r = task >> 3;
            int os = (task ^ r) & 7;      // source octet = o ^ (r&7)
            load_lds16(&A16[(size_t)(m0 + r) * K + kc + os * 8], (half_t*)As + tb * 8);
            load_lds16(&Bt [(size_t)(n0 + r) * K + kc + os * 8], (half_t*)Bs + tb * 8);
        }
        __syncthreads();
#pragma unroll
        for (int kk = 0; kk < 2; ++kk) {
            f16x8 af[4], bf[4];
#pragma unroll
            for (int i = 0; i < 4; ++i) {
                int ra = wm + i * 16 + l16;
                int rb = wn + i * 16 + l16;
                int L = kk * 4 + quad;
                af[i] = *(const f16x8*)&As[ra][(L ^ (ra & 7)) * 8];
                bf[i] = *(const f16x8*)&Bs[rb][(L ^ (rb & 7)) * 8];
            }
#pragma unroll
            for (int i = 0; i < 4; ++i)
#pragma unroll
                for (int j = 0; j < 4; ++j)
                    acc[i][j] = __builtin_amdgcn_mfma_f32_16x16x32_f16(af[i], bf[j], acc[i][j], 0, 0, 0);
        }
        __syncthreads();
    }
    // C/D layout: col=lane&15, row=quad*4+reg (dtype-independent, verified)
#pragma unroll
    for (int i = 0; i < 4; ++i)
#pragma unroll
        for (int j = 0; j < 4; ++j) {
            int col = n0 + wn + j * 16 + l16;
            int rowb = m0 + wm + i * 16 + quad * 4;
#pragma unroll
            for (int rg = 0; rg < 4; ++rg)
                atomicAdd(&C[(size_t)(rowb + rg) * N + col], acc[i][j][rg]);
        }
}

// ---------------------------------------------------------------------------
// RoPE in place on fused qkv buffer [512][6144].
__global__ void rope_kernel(float* __restrict__ t, const float* __restrict__ fc,
                            const float* __restrict__ fs, int colbase, int hmask,
                            int hshift, int total_pairs) {
    int p = blockIdx.x * 256 + threadIdx.x;
    if (p >= total_pairs) return;
    int d2 = p & 63;
    int rest = p >> 6;
    int h = rest & hmask;
    int bi = rest >> hshift;
    float c = fc[(bi & 127) * 64 + d2], s = fs[(bi & 127) * 64 + d2];
    float* q = t + (size_t)bi * NQKV + colbase + h * 128 + d2 * 2;
    float re = q[0], im = q[1];
    q[0] = re * c - im * s;
    q[1] = re * s + im * c;
}

// ---------------------------------------------------------------------------
// scores: P[bh][i][j] = scale * q_i . k_j + mask;  q,k inside qkv buffer.
__global__ __launch_bounds__(256, 2)
void attn_scores_kernel(const float* __restrict__ qkv, const float* __restrict__ mask,
                        float* __restrict__ P) {
    const int bh = blockIdx.x;
    const int b = bh >> 5, h = bh & 31, kv = h >> 2;
    __shared__ float Qs[16][132];
    __shared__ float Ks[16][132];
    const int tid = threadIdx.x;
    const int tx = tid & 15, ty = tid >> 4;

    float acc[8][8];
#pragma unroll
    for (int i = 0; i < 8; ++i)
#pragma unroll
        for (int j = 0; j < 8; ++j) acc[i][j] = 0.f;

    for (int d0 = 0; d0 < HD_; d0 += 16) {
#pragma unroll
        for (int t = 0; t < 2; ++t) {
            int task = tid + t * 256;
            int rr = task >> 2, c = task & 3;
            int dd = d0 + c * 4;
            float4 a4 = *(const float4*)&qkv[(size_t)(b * S_ + rr) * NQKV + h * 128 + dd];
            Qs[c * 4 + 0][rr] = a4.x; Qs[c * 4 + 1][rr] = a4.y;
            Qs[c * 4 + 2][rr] = a4.z; Qs[c * 4 + 3][rr] = a4.w;
            float4 k4 = *(const float4*)&qkv[(size_t)(b * S_ + rr) * NQKV + 4096 + kv * 128 + dd];
            Ks[c * 4 + 0][rr] = k4.x; Ks[c * 4 + 1][rr] = k4.y;
            Ks[c * 4 + 2][rr] = k4.z; Ks[c * 4 + 3][rr] = k4.w;
        }
        __syncthreads();
#pragma unroll
        for (int kk = 0; kk < 16; ++kk) {
            float a[8], bb[8];
            *(float4*)&a[0]  = *(const float4*)&Qs[kk][ty * 4];
            *(float4*)&a[4]  = *(const float4*)&Qs[kk][64 + ty * 4];
            *(float4*)&bb[0] = *(const float4*)&Ks[kk][tx * 4];
            *(float4*)&bb[4] = *(const float4*)&Ks[kk][64 + tx * 4];
#pragma unroll
            for (int i = 0; i < 8; ++i)
#pragma unroll
                for (int j = 0; j < 8; ++j)
                    acc[i][j] = fmaf(a[i], bb[j], acc[i][j]);
        }
        __syncthreads();
    }
#pragma unroll
    for (int ih = 0; ih < 2; ++ih)
#pragma unroll
        for (int i = 0; i < 4; ++i) {
            int row = ih * 64 + ty * 4 + i;
#pragma unroll
            for (int jh = 0; jh < 2; ++jh) {
                int col = jh * 64 + tx * 4;
                float4 r4;
                r4.x = acc[ih*4+i][jh*4+0] * SCALE_ + mask[row * S_ + col + 0];
                r4.y = acc[ih*4+i][jh*4+1] * SCALE_ + mask[row * S_ + col + 1];
                r4.z = acc[ih*4+i][jh*4+2] * SCALE_ + mask[row * S_ + col + 2];
                r4.w = acc[ih*4+i][jh*4+3] * SCALE_ + mask[row * S_ + col + 3];
                *(float4*)&P[((size_t)bh * S_ + row) * S_ + col] = r4;
            }
        }
}

// ---------------------------------------------------------------------------
// softmax over rows of length 128; one wave per row.
__global__ void softmax_kernel(float* __restrict__ P, int rows) {
    int rI = blockIdx.x * 4 + (threadIdx.x >> 6);
    if (rI >= rows) return;
    int lane = threadIdx.x & 63;
    float* row = P + (size_t)rI * 128;
    float x0 = row[lane], x1 = row[lane + 64];
    float m = fmaxf(x0, x1);
#pragma unroll
    for (int off = 32; off >= 1; off >>= 1)
        m = fmaxf(m, __shfl_xor(m, off, 64));
    float e0 = expf(x0 - m), e1 = expf(x1 - m);
    float s = e0 + e1;
#pragma unroll
    for (int off = 32; off >= 1; off >>= 1)
        s += __shfl_xor(s, off, 64);
    float inv = 1.0f / s;
    row[lane] = e0 * inv;
    row[lane + 64] = e1 * inv;
}

// ---------------------------------------------------------------------------
// PV: atb[b,i,h,:] = P[bh] @ V[b,:,kv,:];  V inside qkv buffer.
__global__ __launch_bounds__(256, 2)
void attn_pv_kernel(const float* __restrict__ P, const float* __restrict__ qkv,
                    float* __restrict__ atb) {
    const int bh = blockIdx.x;
    const int b = bh >> 5, h = bh & 31, kv = h >> 2;
    __shared__ float Ps[16][132];
    __shared__ float Vs[16][132];
    const int tid = threadIdx.x;
    const int tx = tid & 15, ty = tid >> 4;

    float acc[8][8];
#pragma unroll
    for (int i = 0; i < 8; ++i)
#pragma unroll
        for (int j = 0; j < 8; ++j) acc[i][j] = 0.f;

    for (int j0 = 0; j0 < S_; j0 += 16) {
#pragma unroll
        for (int t = 0; t < 2; ++t) {
            int task = tid + t * 256;
            int rr = task >> 2, c = task & 3;
            float4 p4 = *(const float4*)&P[((size_t)bh * S_ + rr) * S_ + j0 + c * 4];
            Ps[c * 4 + 0][rr] = p4.x; Ps[c * 4 + 1][rr] = p4.y;
            Ps[c * 4 + 2][rr] = p4.z; Ps[c * 4 + 3][rr] = p4.w;
            int rw = task >> 5, cw = task & 31;
            float4 v4 = *(const float4*)&qkv[(size_t)(b * S_ + j0 + rw) * NQKV + 5120 + kv * 128 + cw * 4];
            *(float4*)&Vs[rw][cw * 4] = v4;
        }
        __syncthreads();
#pragma unroll
        for (int kk = 0; kk < 16; ++kk) {
            float a[8], bb[8];
            *(float4*)&a[0]  = *(const float4*)&Ps[kk][ty * 4];
            *(float4*)&a[4]  = *(const float4*)&Ps[kk][64 + ty * 4];
            *(float4*)&bb[0] = *(const float4*)&Vs[kk][tx * 4];
            *(float4*)&bb[4] = *(const float4*)&Vs[kk][64 + tx * 4];
#pragma unroll
            for (int i = 0; i < 8; ++i)
#pragma unroll
                for (int j = 0; j < 8; ++j)
                    acc[i][j] = fmaf(a[i], bb[j], acc[i][j]);
        }
        __syncthreads();
    }
#pragma unroll
    for (int ih = 0; ih < 2; ++ih)
#pragma unroll
        for (int i = 0; i < 4; ++i) {
            int row = ih * 64 + ty * 4 + i;
#pragma unroll
            for (int jh = 0; jh < 2; ++jh) {
                int col = jh * 64 + tx * 4;
                float4 r4;
                r4.x = acc[ih*4+i][jh*4+0];
                r4.y = acc[ih*4+i][jh*4+1];
                r4.z = acc[ih*4+i][jh*4+2];
                r4.w = acc[ih*4+i][jh*4+3];
                *(float4*)&atb[((size_t)(b * S_ + row)) * 4096 + h * 128 + col] = r4;
            }
        }
}

// ---------------------------------------------------------------------------
extern "C" void kernel_launch(void* const* d_in, const int* in_sizes, int n_in,
                              void* d_out, int out_size, void* d_ws, size_t ws_size,
                              hipStream_t stream) {
    const float* x    = (const float*)d_in[0];
    const float* fc   = (const float*)d_in[2];
    const float* fs   = (const float*)d_in[3];
    const float* mask = (const float*)d_in[4];
    const float* wq   = (const float*)d_in[7];
    const float* bq   = (const float*)d_in[8];
    const float* wk   = (const float*)d_in[9];
    const float* bk   = (const float*)d_in[10];
    const float* wv   = (const float*)d_in[11];
    const float* bv   = (const float*)d_in[12];
    const float* wo   = (const float*)d_in[13];
    const float* bo   = (const float*)d_in[14];
    float* out = (float*)d_out;

    float*  ws  = (float*)d_ws;
    float*  qkv = ws;                        // 512*6144      = 3,145,728 f
    float*  Pb  = qkv + 3145728;             // 4*32*128*128  = 2,097,152 f
    float*  atb = Pb + 2097152;              // 512*4096      = 2,097,152 f
    half_t* x16 = (half_t*)(atb + 2097152);  // 512*4096 halfs (1,048,576 f)
    half_t* a16 = x16 + 2097152;             // 512*4096 halfs
    half_t* Wt  = a16 + 2097152;             // 6144*4096 halfs (12,582,912 f) => ~88 MB total

    // --- weights: fused QKV transpose to fp16 [6144][4096] ---
    transpose_qkv<<<dim3(96, 64), 256, 0, stream>>>(wq, wk, wv, Wt);
    // --- x -> fp16 ---
    convert_f16<<<2048, 256, 0, stream>>>(x, x16, 524288);
    // --- fused QKV projection ---
    init_qkv_bias<<<dim3(24, 512), 256, 0, stream>>>(qkv, bq, bk, bv);
    gemm_f16<<<dim3(48, 4, 8), 256, 0, stream>>>(x16, Wt, qkv, NQKV, 4096, 512);

    // --- RoPE (q: 32 heads, k: 8 heads) ---
    rope_kernel<<<4096, 256, 0, stream>>>(qkv, fc, fs, 0,    31, 5, 1048576);
    rope_kernel<<<1024, 256, 0, stream>>>(qkv, fc, fs, 4096,  7, 3, 262144);

    // --- attention (fp32) ---
    attn_scores_kernel<<<B_ * H_, 256, 0, stream>>>(qkv, mask, Pb);
    softmax_kernel<<<4096, 256, 0, stream>>>(Pb, B_ * H_ * S_);
    attn_pv_kernel<<<B_ * H_, 256, 0, stream>>>(Pb, qkv, atb);

    // --- output projection ---
    transpose_qkv<<<dim3(64, 64), 256, 0, stream>>>(wo, wo, wo, Wt);  // nt<64 path only
    convert_f16<<<2048, 256, 0, stream>>>(atb, a16, 524288);
    init_bias_kernel<<<8192, 256, 0, stream>>>(out, bo, 4095, 2097152);
    gemm_f16<<<dim3(32, 4, 8), 256, 0, stream>>>(a16, Wt, out, 4096, 4096, 512);
}

// Round 4
// 334.470 us; speedup vs baseline: 3.3114x; 1.2709x over previous
//
#include <hip/hip_runtime.h>
#include <math.h>

// GroupedQueryAttention: B=4,S=128,D=4096,H=32,KV=8,HD=128,REP=4
// Round 4: split-K -> partial buffers + fused reduce (no atomics).
//   r3 showed 25M atomicAdd/dispatch = atomic-throughput wall (92us, all pipes idle).
//   QKV reduce fuses bias+RoPE; O reduce fuses bias. Attention trio unchanged.

#define B_   4
#define S_   128
#define D_   4096
#define H_   32
#define KV_  8
#define HD_  128
#define M_   (B_ * S_)        // 512 rows
#define NQKV 6144
#define SCALE_ 0.088388347648318447f  // 1/sqrt(128)

typedef _Float16 half_t;
typedef half_t f16x8 __attribute__((ext_vector_type(8)));
typedef float  f32x4 __attribute__((ext_vector_type(4)));
typedef unsigned short ushort;

__device__ inline void load_lds16(const void* g, void* l) {
    __builtin_amdgcn_global_load_lds((const __attribute__((address_space(1))) void*)g,
                                     (__attribute__((address_space(3))) void*)l,
                                     16, 0, 0);
}

// ---------------------------------------------------------------------------
// fp32 -> fp16 (float4 granules)
__global__ void convert_f16(const float* __restrict__ in, half_t* __restrict__ out,
                            int total4) {
    int i = blockIdx.x * 256 + threadIdx.x;
    if (i >= total4) return;
    float4 f = ((const float4*)in)[i];
    __align__(8) half_t h4[4] = {(half_t)f.x, (half_t)f.y, (half_t)f.z, (half_t)f.w};
    ((uint2*)out)[i] = *(uint2*)h4;
}

// ---------------------------------------------------------------------------
// Fused W [K][Nsrc] fp32 -> Wt [6144][4096] fp16 transposed. 64x64 tiles.
// grid.x: 0-63 -> wq (N=4096), 64-79 -> wk, 80-95 -> wv.  For wo: grid.x=64.
__global__ __launch_bounds__(256)
void transpose_qkv(const float* __restrict__ wq, const float* __restrict__ wk,
                   const float* __restrict__ wv, half_t* __restrict__ Wt) {
    __shared__ float tile[64][65];
    const int t = threadIdx.x;
    const int nt = blockIdx.x, k0 = blockIdx.y * 64;
    const float* src; int Nsrc, nsrc0, ndst0;
    if (nt < 64)      { src = wq; Nsrc = 4096; nsrc0 = nt * 64;        ndst0 = nt * 64; }
    else if (nt < 80) { src = wk; Nsrc = 1024; nsrc0 = (nt - 64) * 64; ndst0 = 4096 + (nt - 64) * 64; }
    else              { src = wv; Nsrc = 1024; nsrc0 = (nt - 80) * 64; ndst0 = 5120 + (nt - 80) * 64; }
#pragma unroll
    for (int p = 0; p < 4; ++p) {
        int idx = t + p * 256;
        int r = idx >> 4, c4 = idx & 15;
        float4 w4 = *(const float4*)&src[(size_t)(k0 + r) * Nsrc + nsrc0 + c4 * 4];
        tile[r][c4 * 4 + 0] = w4.x; tile[r][c4 * 4 + 1] = w4.y;
        tile[r][c4 * 4 + 2] = w4.z; tile[r][c4 * 4 + 3] = w4.w;
    }
    __syncthreads();
    const int n = t >> 2, kq = t & 3;
    __align__(16) half_t hs[16];
#pragma unroll
    for (int i = 0; i < 16; ++i)
        hs[i] = (half_t)tile[kq * 16 + i][n];
    size_t ob = (size_t)(ndst0 + n) * 4096 + k0 + kq * 16;
    *(uint4*)&Wt[ob]     = *(uint4*)&hs[0];
    *(uint4*)&Wt[ob + 8] = *(uint4*)&hs[8];
}

// ---------------------------------------------------------------------------
// Part[z][M][N] = A16[M,K-slice] @ Bt[N,K-slice]^T, fp16 in, fp32 out (plain
// stores, NO atomics). Tile 128x128, BK=64, 4 waves, XOR-swizzled LDS +
// global_load_lds(16B).
__global__ __launch_bounds__(256, 3)
void gemm_f16(const half_t* __restrict__ A16, const half_t* __restrict__ Bt,
              float* __restrict__ Part, int N, int K, int kslice) {
    __shared__ __align__(16) half_t As[128][64];
    __shared__ __align__(16) half_t Bs[128][64];
    const int tid = threadIdx.x;
    const int m0 = blockIdx.y * 128, n0 = blockIdx.x * 128;
    const int kbase = blockIdx.z * kslice;
    const int lane = tid & 63;
    const int quad = lane >> 4, l16 = lane & 15;
    const int w = tid >> 6;
    const int wm = (w & 1) * 64, wn = (w >> 1) * 64;
    const int tB = tid & 192;     // wave-uniform task base

    f32x4 acc[4][4] = {};

    for (int kc = kbase; kc < kbase + kslice; kc += 64) {
#pragma unroll
        for (int p = 0; p < 4; ++p) {
            int tb = p * 256 + tB;        // uniform within wave
            int task = tb + lane;
            int r = task >> 3;
            int os = (task ^ r) & 7;      // source octet = logical ^ (r&7)
            load_lds16(&A16[(size_t)(m0 + r) * K + kc + os * 8], (half_t*)As + tb * 8);
            load_lds16(&Bt [(size_t)(n0 + r) * K + kc + os * 8], (half_t*)Bs + tb * 8);
        }
        __syncthreads();
#pragma unroll
        for (int kk = 0; kk < 2; ++kk) {
            f16x8 af[4], bf[4];
#pragma unroll
            for (int i = 0; i < 4; ++i) {
                int ra = wm + i * 16 + l16;
                int rb = wn + i * 16 + l16;
                int L = kk * 4 + quad;
                af[i] = *(const f16x8*)&As[ra][(L ^ (ra & 7)) * 8];
                bf[i] = *(const f16x8*)&Bs[rb][(L ^ (rb & 7)) * 8];
            }
#pragma unroll
            for (int i = 0; i < 4; ++i)
#pragma unroll
                for (int j = 0; j < 4; ++j)
                    acc[i][j] = __builtin_amdgcn_mfma_f32_16x16x32_f16(af[i], bf[j], acc[i][j], 0, 0, 0);
        }
        __syncthreads();
    }
    // plain scalar stores into this z-slice's partial buffer
    float* Cp = Part + (size_t)blockIdx.z * ((size_t)M_ * N);
#pragma unroll
    for (int i = 0; i < 4; ++i)
#pragma unroll
        for (int j = 0; j < 4; ++j) {
            int col = n0 + wn + j * 16 + l16;
            int rowb = m0 + wm + i * 16 + quad * 4;
#pragma unroll
            for (int rg = 0; rg < 4; ++rg)
                Cp[(size_t)(rowb + rg) * N + col] = acc[i][j][rg];
        }
}

// ---------------------------------------------------------------------------
// qkv[row][col] = sum_z Part[z][row][col] + bias, with RoPE on q/k regions.
// One thread per (row, col-pair). Grid (12, 512).
__global__ void qkv_reduce_rope(const float* __restrict__ Part, int nz,
                                const float* __restrict__ bq, const float* __restrict__ bk,
                                const float* __restrict__ bv,
                                const float* __restrict__ fc, const float* __restrict__ fs,
                                float* __restrict__ qkv) {
    const int row = blockIdx.y;
    const int col = (blockIdx.x * 256 + threadIdx.x) * 2;
    const size_t off = (size_t)row * NQKV + col;
    float2 s = *(const float2*)&Part[off];
    for (int z = 1; z < nz; ++z) {
        float2 p = *(const float2*)&Part[(size_t)z * (M_ * NQKV) + off];
        s.x += p.x; s.y += p.y;
    }
    float2 bi;
    if (col < 4096)      bi = *(const float2*)&bq[col];
    else if (col < 5120) bi = *(const float2*)&bk[col - 4096];
    else                 bi = *(const float2*)&bv[col - 5120];
    s.x += bi.x; s.y += bi.y;
    if (col < 5120) {   // rope on q and k
        int d2 = (col >> 1) & 63;
        int i = row & 127;
        float c = fc[i * 64 + d2], sn = fs[i * 64 + d2];
        float re = s.x, im = s.y;
        s.x = re * c - im * sn;
        s.y = re * sn + im * c;
    }
    *(float2*)&qkv[off] = s;
}

// ---------------------------------------------------------------------------
// out = sum_z PartO[z] + bo.  One thread per float4. Grid 2048.
__global__ void o_reduce(const float* __restrict__ Part, int nz,
                         const float* __restrict__ bo, float* __restrict__ out) {
    const size_t off = (size_t)(blockIdx.x * 256 + threadIdx.x) * 4;
    float4 s = *(const float4*)&Part[off];
    for (int z = 1; z < nz; ++z) {
        float4 p = *(const float4*)&Part[(size_t)z * (M_ * 4096) + off];
        s.x += p.x; s.y += p.y; s.z += p.z; s.w += p.w;
    }
    float4 b = *(const float4*)&bo[off & 4095];
    s.x += b.x; s.y += b.y; s.z += b.z; s.w += b.w;
    *(float4*)&out[off] = s;
}

// ---------------------------------------------------------------------------
// scores: P[bh][i][j] = scale * q_i . k_j + mask;  q,k inside qkv buffer.
__global__ __launch_bounds__(256, 2)
void attn_scores_kernel(const float* __restrict__ qkv, const float* __restrict__ mask,
                        float* __restrict__ P) {
    const int bh = blockIdx.x;
    const int b = bh >> 5, h = bh & 31, kv = h >> 2;
    __shared__ float Qs[16][132];
    __shared__ float Ks[16][132];
    const int tid = threadIdx.x;
    const int tx = tid & 15, ty = tid >> 4;

    float acc[8][8];
#pragma unroll
    for (int i = 0; i < 8; ++i)
#pragma unroll
        for (int j = 0; j < 8; ++j) acc[i][j] = 0.f;

    for (int d0 = 0; d0 < HD_; d0 += 16) {
#pragma unroll
        for (int t = 0; t < 2; ++t) {
            int task = tid + t * 256;
            int rr = task >> 2, c = task & 3;
            int dd = d0 + c * 4;
            float4 a4 = *(const float4*)&qkv[(size_t)(b * S_ + rr) * NQKV + h * 128 + dd];
            Qs[c * 4 + 0][rr] = a4.x; Qs[c * 4 + 1][rr] = a4.y;
            Qs[c * 4 + 2][rr] = a4.z; Qs[c * 4 + 3][rr] = a4.w;
            float4 k4 = *(const float4*)&qkv[(size_t)(b * S_ + rr) * NQKV + 4096 + kv * 128 + dd];
            Ks[c * 4 + 0][rr] = k4.x; Ks[c * 4 + 1][rr] = k4.y;
            Ks[c * 4 + 2][rr] = k4.z; Ks[c * 4 + 3][rr] = k4.w;
        }
        __syncthreads();
#pragma unroll
        for (int kk = 0; kk < 16; ++kk) {
            float a[8], bb[8];
            *(float4*)&a[0]  = *(const float4*)&Qs[kk][ty * 4];
            *(float4*)&a[4]  = *(const float4*)&Qs[kk][64 + ty * 4];
            *(float4*)&bb[0] = *(const float4*)&Ks[kk][tx * 4];
            *(float4*)&bb[4] = *(const float4*)&Ks[kk][64 + tx * 4];
#pragma unroll
            for (int i = 0; i < 8; ++i)
#pragma unroll
                for (int j = 0; j < 8; ++j)
                    acc[i][j] = fmaf(a[i], bb[j], acc[i][j]);
        }
        __syncthreads();
    }
#pragma unroll
    for (int ih = 0; ih < 2; ++ih)
#pragma unroll
        for (int i = 0; i < 4; ++i) {
            int row = ih * 64 + ty * 4 + i;
#pragma unroll
            for (int jh = 0; jh < 2; ++jh) {
                int col = jh * 64 + tx * 4;
                float4 r4;
                r4.x = acc[ih*4+i][jh*4+0] * SCALE_ + mask[row * S_ + col + 0];
                r4.y = acc[ih*4+i][jh*4+1] * SCALE_ + mask[row * S_ + col + 1];
                r4.z = acc[ih*4+i][jh*4+2] * SCALE_ + mask[row * S_ + col + 2];
                r4.w = acc[ih*4+i][jh*4+3] * SCALE_ + mask[row * S_ + col + 3];
                *(float4*)&P[((size_t)bh * S_ + row) * S_ + col] = r4;
            }
        }
}

// ---------------------------------------------------------------------------
// softmax over rows of length 128; one wave per row.
__global__ void softmax_kernel(float* __restrict__ P, int rows) {
    int rI = blockIdx.x * 4 + (threadIdx.x >> 6);
    if (rI >= rows) return;
    int lane = threadIdx.x & 63;
    float* row = P + (size_t)rI * 128;
    float x0 = row[lane], x1 = row[lane + 64];
    float m = fmaxf(x0, x1);
#pragma unroll
    for (int off = 32; off >= 1; off >>= 1)
        m = fmaxf(m, __shfl_xor(m, off, 64));
    float e0 = expf(x0 - m), e1 = expf(x1 - m);
    float s = e0 + e1;
#pragma unroll
    for (int off = 32; off >= 1; off >>= 1)
        s += __shfl_xor(s, off, 64);
    float inv = 1.0f / s;
    row[lane] = e0 * inv;
    row[lane + 64] = e1 * inv;
}

// ---------------------------------------------------------------------------
// PV: atb[b,i,h,:] = P[bh] @ V[b,:,kv,:];  V inside qkv buffer.
__global__ __launch_bounds__(256, 2)
void attn_pv_kernel(const float* __restrict__ P, const float* __restrict__ qkv,
                    float* __restrict__ atb) {
    const int bh = blockIdx.x;
    const int b = bh >> 5, h = bh & 31, kv = h >> 2;
    __shared__ float Ps[16][132];
    __shared__ float Vs[16][132];
    const int tid = threadIdx.x;
    const int tx = tid & 15, ty = tid >> 4;

    float acc[8][8];
#pragma unroll
    for (int i = 0; i < 8; ++i)
#pragma unroll
        for (int j = 0; j < 8; ++j) acc[i][j] = 0.f;

    for (int j0 = 0; j0 < S_; j0 += 16) {
#pragma unroll
        for (int t = 0; t < 2; ++t) {
            int task = tid + t * 256;
            int rr = task >> 2, c = task & 3;
            float4 p4 = *(const float4*)&P[((size_t)bh * S_ + rr) * S_ + j0 + c * 4];
            Ps[c * 4 + 0][rr] = p4.x; Ps[c * 4 + 1][rr] = p4.y;
            Ps[c * 4 + 2][rr] = p4.z; Ps[c * 4 + 3][rr] = p4.w;
            int rw = task >> 5, cw = task & 31;
            float4 v4 = *(const float4*)&qkv[(size_t)(b * S_ + j0 + rw) * NQKV + 5120 + kv * 128 + cw * 4];
            *(float4*)&Vs[rw][cw * 4] = v4;
        }
        __syncthreads();
#pragma unroll
        for (int kk = 0; kk < 16; ++kk) {
            float a[8], bb[8];
            *(float4*)&a[0]  = *(const float4*)&Ps[kk][ty * 4];
            *(float4*)&a[4]  = *(const float4*)&Ps[kk][64 + ty * 4];
            *(float4*)&bb[0] = *(const float4*)&Vs[kk][tx * 4];
            *(float4*)&bb[4] = *(const float4*)&Vs[kk][64 + tx * 4];
#pragma unroll
            for (int i = 0; i < 8; ++i)
#pragma unroll
                for (int j = 0; j < 8; ++j)
                    acc[i][j] = fmaf(a[i], bb[j], acc[i][j]);
        }
        __syncthreads();
    }
#pragma unroll
    for (int ih = 0; ih < 2; ++ih)
#pragma unroll
        for (int i = 0; i < 4; ++i) {
            int row = ih * 64 + ty * 4 + i;
#pragma unroll
            for (int jh = 0; jh < 2; ++jh) {
                int col = jh * 64 + tx * 4;
                float4 r4;
                r4.x = acc[ih*4+i][jh*4+0];
                r4.y = acc[ih*4+i][jh*4+1];
                r4.z = acc[ih*4+i][jh*4+2];
                r4.w = acc[ih*4+i][jh*4+3];
                *(float4*)&atb[((size_t)(b * S_ + row)) * 4096 + h * 128 + col] = r4;
            }
        }
}

// ---------------------------------------------------------------------------
extern "C" void kernel_launch(void* const* d_in, const int* in_sizes, int n_in,
                              void* d_out, int out_size, void* d_ws, size_t ws_size,
                              hipStream_t stream) {
    const float* x    = (const float*)d_in[0];
    const float* fc   = (const float*)d_in[2];
    const float* fs   = (const float*)d_in[3];
    const float* mask = (const float*)d_in[4];
    const float* wq   = (const float*)d_in[7];
    const float* bq   = (const float*)d_in[8];
    const float* wk   = (const float*)d_in[9];
    const float* bk   = (const float*)d_in[10];
    const float* wv   = (const float*)d_in[11];
    const float* bv   = (const float*)d_in[12];
    const float* wo   = (const float*)d_in[13];
    const float* bo   = (const float*)d_in[14];
    float* out = (float*)d_out;

    // Layout (floats). Region B (Part) aliases Pb/atb across disjoint lifetimes:
    //   Part live: [gemmQKV, reduceQKV] and [gemmO, reduceO]
    //   Pb live:   [scores, pv]   atb live: [pv, convert a16]   -- all between.
    float*  ws   = (float*)d_ws;
    float*  qkv  = ws;                        // 3,145,728
    half_t* x16  = (half_t*)(qkv + 3145728);  // 1,048,576 f
    half_t* a16  = (half_t*)(qkv + 4194304);  // 1,048,576 f
    half_t* Wt   = (half_t*)(qkv + 5242880);  // 12,582,912 f (6144x4096 halfs)
    float*  Part = qkv + 17825792;            // z*3,145,728 f
    float*  Pb   = Part;                      // 2,097,152 f (attn phase)
    float*  atb  = Part + 2097152;            // 2,097,152 f (attn phase)

    // split-K factor: z=4 needs ~122 MB of ws; fall back to z=2 (~97 MB).
    const int z = (ws_size >= (size_t)30408704 * 4) ? 4 : 2;
    const int kslice = 4096 / z;

    // --- weights: fused QKV transpose to fp16 [6144][4096] ---
    transpose_qkv<<<dim3(96, 64), 256, 0, stream>>>(wq, wk, wv, Wt);
    // --- x -> fp16 ---
    convert_f16<<<2048, 256, 0, stream>>>(x, x16, 524288);
    // --- fused QKV projection -> partials -> reduce(+bias+rope) ---
    gemm_f16<<<dim3(48, 4, z), 256, 0, stream>>>(x16, Wt, Part, NQKV, 4096, kslice);
    qkv_reduce_rope<<<dim3(12, 512), 256, 0, stream>>>(Part, z, bq, bk, bv, fc, fs, qkv);

    // --- attention (fp32) ---
    attn_scores_kernel<<<B_ * H_, 256, 0, stream>>>(qkv, mask, Pb);
    softmax_kernel<<<4096, 256, 0, stream>>>(Pb, B_ * H_ * S_);
    attn_pv_kernel<<<B_ * H_, 256, 0, stream>>>(Pb, qkv, atb);

    // --- output projection ---
    transpose_qkv<<<dim3(64, 64), 256, 0, stream>>>(wo, wo, wo, Wt);  // nt<64 path
    convert_f16<<<2048, 256, 0, stream>>>(atb, a16, 524288);
    gemm_f16<<<dim3(32, 4, z), 256, 0, stream>>>(a16, Wt, Part, 4096, 4096, kslice);
    o_reduce<<<2048, 256, 0, stream>>>(Part, z, bo, out);
}

// Round 5
// 303.893 us; speedup vs baseline: 3.6445x; 1.1006x over previous
//
#include <hip/hip_runtime.h>
#include <math.h>

// GroupedQueryAttention: B=4,S=128,D=4096,H=32,KV=8,HD=128,REP=4
// Round 5: fp16 end-to-end attention path.
//   - qkv_reduce emits rope'd q16/k16 and transposed vt16 (fp16)
//   - fused_attn: QK^T -> softmax -> PV in one block (MFMA, LDS-resident)
//   - attn writes a16 directly for the O gemm (no convert dispatch)
//   - transpose: 128n x 64k tiles, float4 LDS writes, 64B stores/thread

#define B_   4
#define S_   128
#define D_   4096
#define H_   32
#define KV_  8
#define HD_  128
#define M_   (B_ * S_)        // 512 rows
#define NQKV 6144
#define SCALE_ 0.088388347648318447f  // 1/sqrt(128)

typedef _Float16 half_t;
typedef half_t f16x8 __attribute__((ext_vector_type(8)));
typedef float  f32x4 __attribute__((ext_vector_type(4)));

__device__ inline void load_lds16(const void* g, void* l) {
    __builtin_amdgcn_global_load_lds((const __attribute__((address_space(1))) void*)g,
                                     (__attribute__((address_space(3))) void*)l,
                                     16, 0, 0);
}

// ---------------------------------------------------------------------------
// fp32 -> fp16 (float4 granules)
__global__ void convert_f16(const float* __restrict__ in, half_t* __restrict__ out,
                            int total4) {
    int i = blockIdx.x * 256 + threadIdx.x;
    if (i >= total4) return;
    float4 f = ((const float4*)in)[i];
    __align__(8) half_t h4[4] = {(half_t)f.x, (half_t)f.y, (half_t)f.z, (half_t)f.w};
    ((uint2*)out)[i] = *(uint2*)h4;
}

// ---------------------------------------------------------------------------
// Fused W [K][Nsrc] fp32 -> Wt [6144][4096] fp16 transposed. 128n x 64k tiles.
// grid.x: 0-31 -> wq (N=4096), 32-39 -> wk, 40-47 -> wv.  For wo: grid.x=32.
__global__ __launch_bounds__(256)
void transpose_wf16(const float* __restrict__ wq, const float* __restrict__ wk,
                    const float* __restrict__ wv, half_t* __restrict__ Wt) {
    __shared__ __align__(16) float tile[64][132];
    const int t = threadIdx.x;
    const int nt = blockIdx.x, k0 = blockIdx.y * 64;
    const float* src; int Nsrc, nsrc0, ndst0;
    if (nt < 32)      { src = wq; Nsrc = 4096; nsrc0 = nt * 128;        ndst0 = nt * 128; }
    else if (nt < 40) { src = wk; Nsrc = 1024; nsrc0 = (nt - 32) * 128; ndst0 = 4096 + (nt - 32) * 128; }
    else              { src = wv; Nsrc = 1024; nsrc0 = (nt - 40) * 128; ndst0 = 5120 + (nt - 40) * 128; }
#pragma unroll
    for (int p = 0; p < 8; ++p) {
        int idx = t + p * 256;
        int r = idx >> 5, c4 = idx & 31;   // 64 rows x 32 float4
        *(float4*)&tile[r][c4 * 4] =
            *(const float4*)&src[(size_t)(k0 + r) * Nsrc + nsrc0 + c4 * 4];
    }
    __syncthreads();
    const int n = t >> 1, kh = t & 1;      // 128 n-rows, 2 k-halves of 32
    __align__(16) half_t hs[32];
#pragma unroll
    for (int i = 0; i < 32; ++i)
        hs[i] = (half_t)tile[kh * 32 + i][n];
    size_t ob = (size_t)(ndst0 + n) * 4096 + k0 + kh * 32;
#pragma unroll
    for (int u = 0; u < 4; ++u)
        *(uint4*)&Wt[ob + u * 8] = *(uint4*)&hs[u * 8];
}

// ---------------------------------------------------------------------------
// Part[z][M][N] = A16[M,K-slice] @ Bt[N,K-slice]^T, fp16 in, fp32 plain stores.
// Tile 128x128, BK=64, 4 waves, XOR-swizzled LDS + global_load_lds(16B).
__global__ __launch_bounds__(256, 3)
void gemm_f16(const half_t* __restrict__ A16, const half_t* __restrict__ Bt,
              float* __restrict__ Part, int N, int K, int kslice) {
    __shared__ __align__(16) half_t As[128][64];
    __shared__ __align__(16) half_t Bs[128][64];
    const int tid = threadIdx.x;
    const int m0 = blockIdx.y * 128, n0 = blockIdx.x * 128;
    const int kbase = blockIdx.z * kslice;
    const int lane = tid & 63;
    const int quad = lane >> 4, l16 = lane & 15;
    const int w = tid >> 6;
    const int wm = (w & 1) * 64, wn = (w >> 1) * 64;
    const int tB = tid & 192;

    f32x4 acc[4][4] = {};

    for (int kc = kbase; kc < kbase + kslice; kc += 64) {
#pragma unroll
        for (int p = 0; p < 4; ++p) {
            int tb = p * 256 + tB;
            int task = tb + lane;
            int r = task >> 3;
            int os = (task ^ r) & 7;
            load_lds16(&A16[(size_t)(m0 + r) * K + kc + os * 8], (half_t*)As + tb * 8);
            load_lds16(&Bt [(size_t)(n0 + r) * K + kc + os * 8], (half_t*)Bs + tb * 8);
        }
        __syncthreads();
#pragma unroll
        for (int kk = 0; kk < 2; ++kk) {
            f16x8 af[4], bf[4];
#pragma unroll
            for (int i = 0; i < 4; ++i) {
                int ra = wm + i * 16 + l16;
                int rb = wn + i * 16 + l16;
                int L = kk * 4 + quad;
                af[i] = *(const f16x8*)&As[ra][(L ^ (ra & 7)) * 8];
                bf[i] = *(const f16x8*)&Bs[rb][(L ^ (rb & 7)) * 8];
            }
#pragma unroll
            for (int i = 0; i < 4; ++i)
#pragma unroll
                for (int j = 0; j < 4; ++j)
                    acc[i][j] = __builtin_amdgcn_mfma_f32_16x16x32_f16(af[i], bf[j], acc[i][j], 0, 0, 0);
        }
        __syncthreads();
    }
    float* Cp = Part + (size_t)blockIdx.z * ((size_t)M_ * N);
#pragma unroll
    for (int i = 0; i < 4; ++i)
#pragma unroll
        for (int j = 0; j < 4; ++j) {
            int col = n0 + wn + j * 16 + l16;
            int rowb = m0 + wm + i * 16 + quad * 4;
#pragma unroll
            for (int rg = 0; rg < 4; ++rg)
                Cp[(size_t)(rowb + rg) * N + col] = acc[i][j][rg];
        }
}

// ---------------------------------------------------------------------------
// sum_z Part + bias + RoPE -> fp16 q16 [M][4096], k16 [M][1024],
// vt16 [B][KV][HD][S] (transposed V for the PV MFMA B-operand).
__global__ void qkv_reduce_rope(const float* __restrict__ Part, int nz,
                                const float* __restrict__ bq, const float* __restrict__ bk,
                                const float* __restrict__ bv,
                                const float* __restrict__ fc, const float* __restrict__ fs,
                                half_t* __restrict__ q16, half_t* __restrict__ k16,
                                half_t* __restrict__ vt16) {
    const int row = blockIdx.y;          // b*128 + i
    const int col = (blockIdx.x * 256 + threadIdx.x) * 2;
    const size_t off = (size_t)row * NQKV + col;
    float2 s = *(const float2*)&Part[off];
    for (int z = 1; z < nz; ++z) {
        float2 p = *(const float2*)&Part[(size_t)z * (M_ * NQKV) + off];
        s.x += p.x; s.y += p.y;
    }
    float2 bi;
    if (col < 4096)      bi = *(const float2*)&bq[col];
    else if (col < 5120) bi = *(const float2*)&bk[col - 4096];
    else                 bi = *(const float2*)&bv[col - 5120];
    s.x += bi.x; s.y += bi.y;
    if (col < 5120) {    // RoPE on q and k (pair-interleaved)
        int d2 = (col >> 1) & 63;
        int i = row & 127;
        float c = fc[i * 64 + d2], sn = fs[i * 64 + d2];
        float re = s.x, im = s.y;
        s.x = re * c - im * sn;
        s.y = re * sn + im * c;
    }
    __align__(4) half_t hh[2] = {(half_t)s.x, (half_t)s.y};
    if (col < 4096) {
        *(unsigned int*)&q16[(size_t)row * 4096 + col] = *(unsigned int*)hh;
    } else if (col < 5120) {
        *(unsigned int*)&k16[(size_t)row * 1024 + (col - 4096)] = *(unsigned int*)hh;
    } else {
        int c = col - 5120;
        int kv = c >> 7, d = c & 127;
        int b = row >> 7, i = row & 127;
        size_t base = ((size_t)(b * 8 + kv) * 128 + d) * 128 + i;
        vt16[base]       = hh[0];
        vt16[base + 128] = hh[1];
    }
}

// ---------------------------------------------------------------------------
// Fused attention: one block per (b, h, 32-row q-chunk). Grid 512.
// QK^T (MFMA) -> scale+causal -> softmax (LDS) -> PV (MFMA) -> a16 fp16.
// LDS: Qs (later P-fp16) + Ks (later Vt) + Ps f32 + red = ~61 KB, 2 blk/CU.
__global__ __launch_bounds__(256, 2)
void fused_attn(const half_t* __restrict__ q16, const half_t* __restrict__ k16,
                const half_t* __restrict__ vt16, half_t* __restrict__ a16) {
    __shared__ __align__(16) half_t Qs[32][136];    // phase2: Pg (fp16 probs)
    __shared__ __align__(16) half_t Ks[128][136];   // phase2: Vt
    __shared__ float Ps[32][132];
    __shared__ float red[32][16];

    const int tid = threadIdx.x;
    const int qi = blockIdx.x & 3, h = (blockIdx.x >> 2) & 31, b = blockIdx.x >> 7;
    const int kv = h >> 2;
    const int qbase = qi * 32;
    const int lane = tid & 63, w = tid >> 6;
    const int quad = lane >> 4, l16 = lane & 15;
    const int m0 = (w & 1) * 16, half64 = (w >> 1) * 64;

    // stage Q (32x128) and K (128x128), coalesced uint4
#pragma unroll
    for (int p = 0; p < 2; ++p) {
        int task = tid + p * 256;
        int r = task >> 4, c = task & 15;
        *(uint4*)&Qs[r][c * 8] =
            *(const uint4*)&q16[((size_t)(b * 128 + qbase + r) * 32 + h) * 128 + c * 8];
    }
#pragma unroll
    for (int p = 0; p < 8; ++p) {
        int task = tid + p * 256;
        int r = task >> 4, c = task & 15;
        *(uint4*)&Ks[r][c * 8] =
            *(const uint4*)&k16[((size_t)(b * 128 + r) * 8 + kv) * 128 + c * 8];
    }
    __syncthreads();

    // phase 1: S = Q K^T  (wave: rows m0..+15, cols half64..+63)
    f32x4 s[4] = {};
#pragma unroll
    for (int kc = 0; kc < 4; ++kc) {
        f16x8 af = *(const f16x8*)&Qs[m0 + l16][kc * 32 + quad * 8];
#pragma unroll
        for (int jb = 0; jb < 4; ++jb) {
            f16x8 bf = *(const f16x8*)&Ks[half64 + jb * 16 + l16][kc * 32 + quad * 8];
            s[jb] = __builtin_amdgcn_mfma_f32_16x16x32_f16(af, bf, s[jb], 0, 0, 0);
        }
    }
    // scale + causal mask -> Ps (C-layout: col=l16, row=quad*4+rg)
#pragma unroll
    for (int jb = 0; jb < 4; ++jb) {
        int j = half64 + jb * 16 + l16;
#pragma unroll
        for (int rg = 0; rg < 4; ++rg) {
            int row = m0 + quad * 4 + rg;
            Ps[row][j] = (j <= qbase + row) ? s[jb][rg] * SCALE_ : -1e30f;
        }
    }
    __syncthreads();

    // softmax: thread t -> row r, 16-col segment seg
    const int r = tid >> 3, seg = tid & 7;
    float mx = -1e30f;
#pragma unroll
    for (int i = 0; i < 16; ++i) mx = fmaxf(mx, Ps[r][seg * 16 + i]);
    red[r][seg] = mx;
    __syncthreads();

    // stage Vt loads early (latency overlap with exp pass); Ks region is dead
    uint4 vstage[8];
#pragma unroll
    for (int p = 0; p < 8; ++p) {
        int task = tid + p * 256;
        int rr = task >> 4, c = task & 15;
        vstage[p] = *(const uint4*)&vt16[((size_t)(b * 8 + kv) * 128 + rr) * 128 + c * 8];
    }
    float m = red[r][0];
#pragma unroll
    for (int i = 1; i < 8; ++i) m = fmaxf(m, red[r][i]);
    float sum = 0.f;
#pragma unroll
    for (int i = 0; i < 16; ++i) {
        float e = __expf(Ps[r][seg * 16 + i] - m);
        Ps[r][seg * 16 + i] = e;
        sum += e;
    }
    red[r][8 + seg] = sum;
#pragma unroll
    for (int p = 0; p < 8; ++p) {
        int task = tid + p * 256;
        int rr = task >> 4, c = task & 15;
        *(uint4*)&Ks[rr][c * 8] = vstage[p];   // Vt[d][j]
    }
    __syncthreads();

    float tot = 0.f;
#pragma unroll
    for (int i = 0; i < 8; ++i) tot += red[r][8 + i];
    float inv = 1.0f / tot;
#pragma unroll
    for (int i = 0; i < 16; ++i)
        Qs[r][seg * 16 + i] = (half_t)(Ps[r][seg * 16 + i] * inv);   // Pg (A-layout)
    __syncthreads();

    // phase 2: O = P V  (wave: rows m0..+15, d-cols half64..+63)
    f32x4 o[4] = {};
#pragma unroll
    for (int jc = 0; jc < 4; ++jc) {
        f16x8 af = *(const f16x8*)&Qs[m0 + l16][jc * 32 + quad * 8];
#pragma unroll
        for (int db = 0; db < 4; ++db) {
            f16x8 bf = *(const f16x8*)&Ks[half64 + db * 16 + l16][jc * 32 + quad * 8];
            o[db] = __builtin_amdgcn_mfma_f32_16x16x32_f16(af, bf, o[db], 0, 0, 0);
        }
    }
#pragma unroll
    for (int db = 0; db < 4; ++db) {
        int d = half64 + db * 16 + l16;
#pragma unroll
        for (int rg = 0; rg < 4; ++rg) {
            int row = m0 + quad * 4 + rg;
            a16[(size_t)(b * 128 + qbase + row) * 4096 + h * 128 + d] = (half_t)o[db][rg];
        }
    }
}

// ---------------------------------------------------------------------------
// out = sum_z PartO[z] + bo.  One thread per float4. Grid 2048.
__global__ void o_reduce(const float* __restrict__ Part, int nz,
                         const float* __restrict__ bo, float* __restrict__ out) {
    const size_t off = (size_t)(blockIdx.x * 256 + threadIdx.x) * 4;
    float4 s = *(const float4*)&Part[off];
    for (int z = 1; z < nz; ++z) {
        float4 p = *(const float4*)&Part[(size_t)z * (M_ * 4096) + off];
        s.x += p.x; s.y += p.y; s.z += p.z; s.w += p.w;
    }
    float4 b = *(const float4*)&bo[off & 4095];
    s.x += b.x; s.y += b.y; s.z += b.z; s.w += b.w;
    *(float4*)&out[off] = s;
}

// ---------------------------------------------------------------------------
extern "C" void kernel_launch(void* const* d_in, const int* in_sizes, int n_in,
                              void* d_out, int out_size, void* d_ws, size_t ws_size,
                              hipStream_t stream) {
    const float* x    = (const float*)d_in[0];
    const float* fc   = (const float*)d_in[2];
    const float* fs   = (const float*)d_in[3];
    const float* wq   = (const float*)d_in[7];
    const float* bq   = (const float*)d_in[8];
    const float* wk   = (const float*)d_in[9];
    const float* bk   = (const float*)d_in[10];
    const float* wv   = (const float*)d_in[11];
    const float* bv   = (const float*)d_in[12];
    const float* wo   = (const float*)d_in[13];
    const float* bo   = (const float*)d_in[14];
    float* out = (float*)d_out;

    half_t* x16  = (half_t*)d_ws;            // 2,097,152 h
    half_t* a16  = x16 + 2097152;            // 2,097,152 h
    half_t* q16  = a16 + 2097152;            // 2,097,152 h
    half_t* k16  = q16 + 2097152;            //   524,288 h
    half_t* vt16 = k16 + 524288;             //   524,288 h
    half_t* Wt   = vt16 + 524288;            // 25,165,824 h
    float*  Part = (float*)(Wt + 25165824);  // z * 3,145,728 f

    // fixed region = 65,011,712 B; z=4 adds 50,331,648 B of partials
    const int z = (ws_size >= (size_t)65011712 + (size_t)4 * 12582912) ? 4 : 2;
    const int kslice = 4096 / z;

    // --- weights: fused QKV transpose to fp16 [6144][4096] ---
    transpose_wf16<<<dim3(48, 64), 256, 0, stream>>>(wq, wk, wv, Wt);
    // --- x -> fp16 ---
    convert_f16<<<2048, 256, 0, stream>>>(x, x16, 524288);
    // --- fused QKV projection -> partials -> reduce(+bias+rope, emit fp16) ---
    gemm_f16<<<dim3(48, 4, z), 256, 0, stream>>>(x16, Wt, Part, NQKV, 4096, kslice);
    qkv_reduce_rope<<<dim3(12, 512), 256, 0, stream>>>(Part, z, bq, bk, bv, fc, fs,
                                                       q16, k16, vt16);
    // --- fused attention (fp16 MFMA), writes a16 directly ---
    fused_attn<<<512, 256, 0, stream>>>(q16, k16, vt16, a16);

    // --- output projection ---
    transpose_wf16<<<dim3(32, 64), 256, 0, stream>>>(wo, wo, wo, Wt);  // nt<32 path
    gemm_f16<<<dim3(32, 4, z), 256, 0, stream>>>(a16, Wt, Part, 4096, 4096, kslice);
    o_reduce<<<2048, 256, 0, stream>>>(Part, z, bo, out);
}

// Round 6
// 293.133 us; speedup vs baseline: 3.7783x; 1.0367x over previous
//
#include <hip/hip_runtime.h>
#include <math.h>

// GroupedQueryAttention: B=4,S=128,D=4096,H=32,KV=8,HD=128,REP=4
// Round 6: slab-tiled fp16 weight layout Wt[k/64][n][64]:
//   - transpose writes 16KB contiguous per block (r5: 128B scattered -> 2.2TB/s)
//   - gemm B-side DMA reads 16KB contiguous regions
//   Packing: x-convert inside QKV-transpose launch; wo-transpose inside the
//   QKV-gemm launch (independent work, complementary pipes).

#define B_   4
#define S_   128
#define D_   4096
#define H_   32
#define KV_  8
#define HD_  128
#define M_   (B_ * S_)        // 512 rows
#define NQKV 6144
#define SCALE_ 0.088388347648318447f  // 1/sqrt(128)

typedef _Float16 half_t;
typedef half_t f16x8 __attribute__((ext_vector_type(8)));
typedef float  f32x4 __attribute__((ext_vector_type(4)));

__device__ inline void load_lds16(const void* g, void* l) {
    __builtin_amdgcn_global_load_lds((const __attribute__((address_space(1))) void*)g,
                                     (__attribute__((address_space(3))) void*)l,
                                     16, 0, 0);
}

// ---------------------------------------------------------------------------
// One 128n x 64k transpose tile: W[k0..+64][nsrc0..+128] fp32 ->
// Wt slab (k0/64): rows ndst0..+128 x 64 halfs  (16KB contiguous write).
__device__ void transpose_tile(const float* __restrict__ src, int Nsrc, int nsrc0,
                               int ndst0, int k0, int Ntot,
                               half_t* __restrict__ Wt, void* ldsraw) {
    float (*tile)[132] = (float(*)[132])ldsraw;   // [64k][128n], pad 132
    const int t = threadIdx.x;
#pragma unroll
    for (int p = 0; p < 8; ++p) {
        int idx = t + p * 256;              // 2048 float4 tasks
        int r = idx >> 5, c4 = idx & 31;    // 64 k-rows x 32 float4
        *(float4*)&tile[r][c4 * 4] =
            *(const float4*)&src[(size_t)(k0 + r) * Nsrc + nsrc0 + c4 * 4];
    }
    __syncthreads();
    const int n = t >> 1, kh = t & 1;       // 128 n-rows, 2 k-halves of 32
    __align__(16) half_t hs[32];
#pragma unroll
    for (int i = 0; i < 32; ++i)
        hs[i] = (half_t)tile[kh * 32 + i][n];
    size_t ob = ((size_t)(k0 >> 6) * Ntot + ndst0 + n) * 64 + kh * 32;
#pragma unroll
    for (int u = 0; u < 4; ++u)
        *(uint4*)&Wt[ob + u * 8] = *(uint4*)&hs[u * 8];
}

// ---------------------------------------------------------------------------
// One 128x128 gemm tile: Part[zi][M][N] = A16[M][4096-slice] @ Wt^T.
// Wt slab-tiled [k/64][N][64]. BK=64, 4 waves, XOR-swizzle + DMA staging.
__device__ void gemm_tile(const half_t* __restrict__ A16, const half_t* __restrict__ Wt,
                          float* __restrict__ Part, int N, int m0, int n0,
                          int zi, int kslice, char* lds) {
    half_t (*As)[64] = (half_t(*)[64])lds;
    half_t (*Bs)[64] = (half_t(*)[64])(lds + 16384);
    const int tid = threadIdx.x;
    const int kbase = zi * kslice;
    const int lane = tid & 63;
    const int quad = lane >> 4, l16 = lane & 15;
    const int w = tid >> 6;
    const int wm = (w & 1) * 64, wn = (w >> 1) * 64;
    const int tB = tid & 192;

    f32x4 acc[4][4] = {};

    for (int kc = kbase; kc < kbase + kslice; kc += 64) {
        const half_t* Bslab = Wt + ((size_t)(kc >> 6) * N + n0) * 64;
#pragma unroll
        for (int p = 0; p < 4; ++p) {
            int tb = p * 256 + tB;          // wave-uniform
            int task = tb + lane;
            int r = task >> 3;
            int os = (task ^ r) & 7;        // XOR swizzle within 64-half row
            load_lds16(&A16[(size_t)(m0 + r) * 4096 + kc + os * 8], (half_t*)As + tb * 8);
            load_lds16(&Bslab[(size_t)r * 64 + os * 8],             (half_t*)Bs + tb * 8);
        }
        __syncthreads();
#pragma unroll
        for (int kk = 0; kk < 2; ++kk) {
            f16x8 af[4], bf[4];
#pragma unroll
            for (int i = 0; i < 4; ++i) {
                int ra = wm + i * 16 + l16;
                int rb = wn + i * 16 + l16;
                int L = kk * 4 + quad;
                af[i] = *(const f16x8*)&As[ra][(L ^ (ra & 7)) * 8];
                bf[i] = *(const f16x8*)&Bs[rb][(L ^ (rb & 7)) * 8];
            }
#pragma unroll
            for (int i = 0; i < 4; ++i)
#pragma unroll
                for (int j = 0; j < 4; ++j)
                    acc[i][j] = __builtin_amdgcn_mfma_f32_16x16x32_f16(af[i], bf[j], acc[i][j], 0, 0, 0);
        }
        __syncthreads();
    }
    float* Cp = Part + (size_t)zi * ((size_t)M_ * N);
#pragma unroll
    for (int i = 0; i < 4; ++i)
#pragma unroll
        for (int j = 0; j < 4; ++j) {
            int col = n0 + wn + j * 16 + l16;
            int rowb = m0 + wm + i * 16 + quad * 4;
#pragma unroll
            for (int rg = 0; rg < 4; ++rg)
                Cp[(size_t)(rowb + rg) * N + col] = acc[i][j][rg];
        }
}

// ---------------------------------------------------------------------------
// Packed: QKV weight transpose (3072 blocks) + x fp32->fp16 (512 blocks).
__global__ __launch_bounds__(256)
void prep_qkv(const float* __restrict__ wq, const float* __restrict__ wk,
              const float* __restrict__ wv, const float* __restrict__ x,
              half_t* __restrict__ Wt, half_t* __restrict__ x16) {
    __shared__ __align__(16) char lds[33792];
    const int bx = blockIdx.x;
    if (bx < 3072) {
        int nt = bx % 48, kt = bx / 48;
        const float* src; int Nsrc, ns0, nd0;
        if (nt < 32)      { src = wq; Nsrc = 4096; ns0 = nt * 128;        nd0 = nt * 128; }
        else if (nt < 40) { src = wk; Nsrc = 1024; ns0 = (nt - 32) * 128; nd0 = 4096 + (nt - 32) * 128; }
        else              { src = wv; Nsrc = 1024; ns0 = (nt - 40) * 128; nd0 = 5120 + (nt - 40) * 128; }
        transpose_tile(src, Nsrc, ns0, nd0, kt * 64, NQKV, Wt, lds);
    } else {
        int i0 = (bx - 3072) * 1024 + threadIdx.x;
#pragma unroll
        for (int j = 0; j < 4; ++j) {
            int i = i0 + j * 256;
            float4 f = ((const float4*)x)[i];
            __align__(8) half_t h4[4] = {(half_t)f.x, (half_t)f.y, (half_t)f.z, (half_t)f.w};
            ((uint2*)x16)[i] = *(uint2*)h4;
        }
    }
}

// ---------------------------------------------------------------------------
// Packed: QKV gemm (gemmBlocks = 192*z) + optional wo transpose (2048 blocks).
__global__ __launch_bounds__(256, 3)
void gemm_qkv_pack(const half_t* __restrict__ x16, const half_t* __restrict__ Wt,
                   float* __restrict__ Part, int kslice, int gemmBlocks,
                   const float* __restrict__ wo, half_t* __restrict__ WtO) {
    __shared__ __align__(16) char lds[33792];
    const int bx = blockIdx.x;
    if (bx < gemmBlocks) {
        int nb = bx % 48, mb = (bx / 48) & 3, zi = bx / 192;
        gemm_tile(x16, Wt, Part, NQKV, mb * 128, nb * 128, zi, kslice, lds);
    } else {
        int t = bx - gemmBlocks;
        int nt = t & 31, kt = t >> 5;       // 32 n-tiles x 64 k-tiles
        transpose_tile(wo, 4096, nt * 128, nt * 128, kt * 64, 4096, WtO, lds);
    }
}

// Fallback standalone wo transpose (small-ws layout).
__global__ __launch_bounds__(256)
void wo_trans(const float* __restrict__ wo, half_t* __restrict__ WtO) {
    __shared__ __align__(16) char lds[33792];
    int nt = blockIdx.x & 31, kt = blockIdx.x >> 5;
    transpose_tile(wo, 4096, nt * 128, nt * 128, kt * 64, 4096, WtO, lds);
}

// O projection gemm.
__global__ __launch_bounds__(256, 3)
void gemm_o(const half_t* __restrict__ a16, const half_t* __restrict__ WtO,
            float* __restrict__ Part, int kslice) {
    __shared__ __align__(16) char lds[33792];
    gemm_tile(a16, WtO, Part, 4096, blockIdx.y * 128, blockIdx.x * 128,
              blockIdx.z, kslice, lds);
}

// ---------------------------------------------------------------------------
// sum_z Part + bias + RoPE -> fp16 q16 [M][4096], k16 [M][1024],
// vt16 [B][KV][HD][S].
__global__ void qkv_reduce_rope(const float* __restrict__ Part, int nz,
                                const float* __restrict__ bq, const float* __restrict__ bk,
                                const float* __restrict__ bv,
                                const float* __restrict__ fc, const float* __restrict__ fs,
                                half_t* __restrict__ q16, half_t* __restrict__ k16,
                                half_t* __restrict__ vt16) {
    const int row = blockIdx.y;          // b*128 + i
    const int col = (blockIdx.x * 256 + threadIdx.x) * 2;
    const size_t off = (size_t)row * NQKV + col;
    float2 s = *(const float2*)&Part[off];
    for (int z = 1; z < nz; ++z) {
        float2 p = *(const float2*)&Part[(size_t)z * (M_ * NQKV) + off];
        s.x += p.x; s.y += p.y;
    }
    float2 bi;
    if (col < 4096)      bi = *(const float2*)&bq[col];
    else if (col < 5120) bi = *(const float2*)&bk[col - 4096];
    else                 bi = *(const float2*)&bv[col - 5120];
    s.x += bi.x; s.y += bi.y;
    if (col < 5120) {    // RoPE (pair-interleaved)
        int d2 = (col >> 1) & 63;
        int i = row & 127;
        float c = fc[i * 64 + d2], sn = fs[i * 64 + d2];
        float re = s.x, im = s.y;
        s.x = re * c - im * sn;
        s.y = re * sn + im * c;
    }
    __align__(4) half_t hh[2] = {(half_t)s.x, (half_t)s.y};
    if (col < 4096) {
        *(unsigned int*)&q16[(size_t)row * 4096 + col] = *(unsigned int*)hh;
    } else if (col < 5120) {
        *(unsigned int*)&k16[(size_t)row * 1024 + (col - 4096)] = *(unsigned int*)hh;
    } else {
        int c = col - 5120;
        int kv = c >> 7, d = c & 127;
        int b = row >> 7, i = row & 127;
        size_t base = ((size_t)(b * 8 + kv) * 128 + d) * 128 + i;
        vt16[base]       = hh[0];
        vt16[base + 128] = hh[1];
    }
}

// ---------------------------------------------------------------------------
// Fused attention: one block per (b, h, 32-row q-chunk). Grid 512.
__global__ __launch_bounds__(256, 2)
void fused_attn(const half_t* __restrict__ q16, const half_t* __restrict__ k16,
                const half_t* __restrict__ vt16, half_t* __restrict__ a16) {
    __shared__ __align__(16) half_t Qs[32][136];    // phase2: P fp16 (A-layout)
    __shared__ __align__(16) half_t Ks[128][136];   // phase2: Vt
    __shared__ float Ps[32][132];
    __shared__ float red[32][16];

    const int tid = threadIdx.x;
    const int qi = blockIdx.x & 3, h = (blockIdx.x >> 2) & 31, b = blockIdx.x >> 7;
    const int kv = h >> 2;
    const int qbase = qi * 32;
    const int lane = tid & 63, w = tid >> 6;
    const int quad = lane >> 4, l16 = lane & 15;
    const int m0 = (w & 1) * 16, half64 = (w >> 1) * 64;

#pragma unroll
    for (int p = 0; p < 2; ++p) {
        int task = tid + p * 256;
        int r = task >> 4, c = task & 15;
        *(uint4*)&Qs[r][c * 8] =
            *(const uint4*)&q16[((size_t)(b * 128 + qbase + r) * 32 + h) * 128 + c * 8];
    }
#pragma unroll
    for (int p = 0; p < 8; ++p) {
        int task = tid + p * 256;
        int r = task >> 4, c = task & 15;
        *(uint4*)&Ks[r][c * 8] =
            *(const uint4*)&k16[((size_t)(b * 128 + r) * 8 + kv) * 128 + c * 8];
    }
    __syncthreads();

    // phase 1: S = Q K^T
    f32x4 s[4] = {};
#pragma unroll
    for (int kc = 0; kc < 4; ++kc) {
        f16x8 af = *(const f16x8*)&Qs[m0 + l16][kc * 32 + quad * 8];
#pragma unroll
        for (int jb = 0; jb < 4; ++jb) {
            f16x8 bf = *(const f16x8*)&Ks[half64 + jb * 16 + l16][kc * 32 + quad * 8];
            s[jb] = __builtin_amdgcn_mfma_f32_16x16x32_f16(af, bf, s[jb], 0, 0, 0);
        }
    }
#pragma unroll
    for (int jb = 0; jb < 4; ++jb) {
        int j = half64 + jb * 16 + l16;
#pragma unroll
        for (int rg = 0; rg < 4; ++rg) {
            int row = m0 + quad * 4 + rg;
            Ps[row][j] = (j <= qbase + row) ? s[jb][rg] * SCALE_ : -1e30f;
        }
    }
    __syncthreads();

    // softmax: thread t -> row r, 16-col segment seg
    const int r = tid >> 3, seg = tid & 7;
    float mx = -1e30f;
#pragma unroll
    for (int i = 0; i < 16; ++i) mx = fmaxf(mx, Ps[r][seg * 16 + i]);
    red[r][seg] = mx;
    __syncthreads();

    uint4 vstage[8];
#pragma unroll
    for (int p = 0; p < 8; ++p) {
        int task = tid + p * 256;
        int rr = task >> 4, c = task & 15;
        vstage[p] = *(const uint4*)&vt16[((size_t)(b * 8 + kv) * 128 + rr) * 128 + c * 8];
    }
    float m = red[r][0];
#pragma unroll
    for (int i = 1; i < 8; ++i) m = fmaxf(m, red[r][i]);
    float sum = 0.f;
#pragma unroll
    for (int i = 0; i < 16; ++i) {
        float e = __expf(Ps[r][seg * 16 + i] - m);
        Ps[r][seg * 16 + i] = e;
        sum += e;
    }
    red[r][8 + seg] = sum;
#pragma unroll
    for (int p = 0; p < 8; ++p) {
        int task = tid + p * 256;
        int rr = task >> 4, c = task & 15;
        *(uint4*)&Ks[rr][c * 8] = vstage[p];   // Vt[d][j]
    }
    __syncthreads();

    float tot = 0.f;
#pragma unroll
    for (int i = 0; i < 8; ++i) tot += red[r][8 + i];
    float inv = 1.0f / tot;
#pragma unroll
    for (int i = 0; i < 16; ++i)
        Qs[r][seg * 16 + i] = (half_t)(Ps[r][seg * 16 + i] * inv);
    __syncthreads();

    // phase 2: O = P V
    f32x4 o[4] = {};
#pragma unroll
    for (int jc = 0; jc < 4; ++jc) {
        f16x8 af = *(const f16x8*)&Qs[m0 + l16][jc * 32 + quad * 8];
#pragma unroll
        for (int db = 0; db < 4; ++db) {
            f16x8 bf = *(const f16x8*)&Ks[half64 + db * 16 + l16][jc * 32 + quad * 8];
            o[db] = __builtin_amdgcn_mfma_f32_16x16x32_f16(af, bf, o[db], 0, 0, 0);
        }
    }
#pragma unroll
    for (int db = 0; db < 4; ++db) {
        int d = half64 + db * 16 + l16;
#pragma unroll
        for (int rg = 0; rg < 4; ++rg) {
            int row = m0 + quad * 4 + rg;
            a16[(size_t)(b * 128 + qbase + row) * 4096 + h * 128 + d] = (half_t)o[db][rg];
        }
    }
}

// ---------------------------------------------------------------------------
// out = sum_z PartO[z] + bo.  One thread per float4. Grid 2048.
__global__ void o_reduce(const float* __restrict__ Part, int nz,
                         const float* __restrict__ bo, float* __restrict__ out) {
    const size_t off = (size_t)(blockIdx.x * 256 + threadIdx.x) * 4;
    float4 s = *(const float4*)&Part[off];
    for (int z = 1; z < nz; ++z) {
        float4 p = *(const float4*)&Part[(size_t)z * (M_ * 4096) + off];
        s.x += p.x; s.y += p.y; s.z += p.z; s.w += p.w;
    }
    float4 b = *(const float4*)&bo[off & 4095];
    s.x += b.x; s.y += b.y; s.z += b.z; s.w += b.w;
    *(float4*)&out[off] = s;
}

// ---------------------------------------------------------------------------
extern "C" void kernel_launch(void* const* d_in, const int* in_sizes, int n_in,
                              void* d_out, int out_size, void* d_ws, size_t ws_size,
                              hipStream_t stream) {
    const float* x    = (const float*)d_in[0];
    const float* fc   = (const float*)d_in[2];
    const float* fs   = (const float*)d_in[3];
    const float* wq   = (const float*)d_in[7];
    const float* bq   = (const float*)d_in[8];
    const float* wk   = (const float*)d_in[9];
    const float* bk   = (const float*)d_in[10];
    const float* wv   = (const float*)d_in[11];
    const float* bv   = (const float*)d_in[12];
    const float* wo   = (const float*)d_in[13];
    const float* bo   = (const float*)d_in[14];
    float* out = (float*)d_out;

    half_t* x16  = (half_t*)d_ws;            //  2,097,152 h
    half_t* a16  = x16 + 2097152;            //  2,097,152 h
    half_t* q16  = a16 + 2097152;            //  2,097,152 h
    half_t* k16  = q16 + 2097152;            //    524,288 h
    half_t* vt16 = k16 + 524288;             //    524,288 h
    half_t* Wt   = vt16 + 524288;            // 25,165,824 h (ends @65,011,712 B)

    // Layout A (packed wo-T): separate WtO after Wt; Part after WtO.
    // Layout B (fallback):    WtO aliases Wt;        Part after Wt.
    const size_t fixedB = 65011712;                       // bytes through Wt
    const size_t fixedA = fixedB + (size_t)16777216 * 2;  // + WtO (32 MB)
    int z; bool packed;
    if      (ws_size >= fixedA + 4 * (size_t)12582912) { packed = true;  z = 4; }
    else if (ws_size >= fixedA + 2 * (size_t)12582912) { packed = true;  z = 2; }
    else if (ws_size >= fixedB + 4 * (size_t)12582912) { packed = false; z = 4; }
    else                                               { packed = false; z = 2; }
    half_t* WtO  = packed ? Wt + 25165824 : Wt;
    float*  Part = (float*)((char*)d_ws + (packed ? fixedA : fixedB));
    const int kslice = 4096 / z;

    // --- QKV weight transpose (tiled) + x convert, one launch ---
    prep_qkv<<<3584, 256, 0, stream>>>(wq, wk, wv, x, Wt, x16);

    // --- QKV gemm (+ wo transpose packed in, layout A) ---
    gemm_qkv_pack<<<192 * z + (packed ? 2048 : 0), 256, 0, stream>>>(
        x16, Wt, Part, kslice, 192 * z, wo, WtO);

    // --- reduce + bias + rope -> fp16 q/k/vt ---
    qkv_reduce_rope<<<dim3(12, 512), 256, 0, stream>>>(Part, z, bq, bk, bv, fc, fs,
                                                       q16, k16, vt16);
    if (!packed)
        wo_trans<<<2048, 256, 0, stream>>>(wo, WtO);

    // --- fused attention ---
    fused_attn<<<512, 256, 0, stream>>>(q16, k16, vt16, a16);

    // --- output projection ---
    gemm_o<<<dim3(32, 4, z), 256, 0, stream>>>(a16, WtO, Part, kslice);
    o_reduce<<<2048, 256, 0, stream>>>(Part, z, bo, out);
}